// Round 9
// baseline (452.253 us; speedup 1.0000x reference)
//
#include <hip/hip_runtime.h>
#include <hip/hip_bf16.h>
#include <math.h>

namespace {
constexpr int B_ = 4, HQ_ = 32, HK_ = 8, G_ = 4, M_ = 16;
constexpr int N_ = 8192, D_ = 128, S_ = 256, O_ = 8;
constexpr int TN = 64;               // n-rows per block
constexpr float TAU  = 1e-3f;        // inlier sign: |dot| below -> exact fp64 recheck
constexpr float TAUO = 1e-4f;        // outlier sign: |dot| below -> exact fp64 recheck
}

typedef short short8 __attribute__((ext_vector_type(8)));
typedef float f32x4 __attribute__((ext_vector_type(4)));
typedef unsigned int uint4_ __attribute__((ext_vector_type(4)));
typedef unsigned int uint2_ __attribute__((ext_vector_type(2)));
typedef unsigned long long ull2 __attribute__((ext_vector_type(2)));

__device__ inline unsigned short f2bf_rne(float f) {
    unsigned u = __float_as_uint(f);
    u += 0x7FFF + ((u >> 16) & 1);
    return (unsigned short)(u >> 16);
}
__device__ inline float bf2f(unsigned short h) {
    return __uint_as_float(((unsigned)h) << 16);
}

// ---------------- kernel P-split: PtHi/PtLo[s][d] = bf16 hi/lo of P[d][s]; Pt32 fp32 ----
__global__ __launch_bounds__(256) void qjl_prept(const float* __restrict__ P,
                                                 unsigned short* __restrict__ PtHi,
                                                 unsigned short* __restrict__ PtLo,
                                                 float* __restrict__ Pt32) {
    const int d = blockIdx.x;      // 0..127
    const int s = threadIdx.x;     // 0..255
    const float f = P[d * S_ + s];
    const unsigned short hb = f2bf_rne(f);
    const float lof = f - bf2f(hb);
    PtHi[s * D_ + d] = hb;
    PtLo[s * D_ + d] = f2bf_rne(lof);
    Pt32[s * D_ + d] = f;
}

// ---------------- kernel A: sqHi[head][m][s] = bf16(q · P); qT[head][d][m] = q^T ----
__global__ __launch_bounds__(256) void qjl_sketch_q(const float* __restrict__ q,
                                                    const float* __restrict__ P,
                                                    unsigned short* __restrict__ sqHi,
                                                    float* __restrict__ qT) {
    __shared__ float qs[M_][D_];
    const int tid = threadIdx.x;
    const size_t blk = blockIdx.x;  // b*HQ + hq
    const float* qb = q + blk * (size_t)(M_ * D_);
    for (int i = tid; i < M_ * D_ / 4; i += 256)
        reinterpret_cast<float4*>(&qs[0][0])[i] = reinterpret_cast<const float4*>(qb)[i];
    __syncthreads();
    float* qtb = qT + blk * (size_t)(D_ * M_);
    for (int i = tid; i < D_ * M_ / 4; i += 256) {
        const int d = i >> 2;
        const int m4 = i & 3;
        float4 v;
        v.x = qs[m4 * 4 + 0][d];
        v.y = qs[m4 * 4 + 1][d];
        v.z = qs[m4 * 4 + 2][d];
        v.w = qs[m4 * 4 + 3][d];
        reinterpret_cast<float4*>(qtb)[i] = v;
    }
    float acc[M_];
#pragma unroll
    for (int m = 0; m < M_; ++m) acc[m] = 0.f;
    const int s = tid;
    for (int d = 0; d < D_; ++d) {
        const float pv = P[d * S_ + s];
#pragma unroll
        for (int m = 0; m < M_; ++m) acc[m] = fmaf(qs[m][d], pv, acc[m]);
    }
    unsigned short* ob = sqHi + blk * (size_t)(M_ * S_);
#pragma unroll
    for (int m = 0; m < M_; ++m) ob[m * S_ + s] = f2bf_rne(acc[m]);
}

// rare cooperative path: exact fp64 sign of k_in[row] . P[:,col]; all 64 lanes participate.
__device__ __noinline__ float qjl_fix_coop(const float* __restrict__ drow,
                                           const float* __restrict__ Pt32,
                                           int col, unsigned long long ip,
                                           float a, int src) {
    const int lane = threadIdx.x & 63;
    const float2 dv = *reinterpret_cast<const float2*>(&drow[2 * lane]);
    const float2 pv = *reinterpret_cast<const float2*>(&Pt32[(size_t)col * D_ + 2 * lane]);
    double p = 0.0;
#pragma unroll
    for (int e = 0; e < 2; ++e) {
        const int d = 2 * lane + e;
        const float v = e ? dv.y : dv.x;
        const float pw = e ? pv.y : pv.x;
        bool isout = false;
#pragma unroll
        for (int j = 0; j < 8; ++j)
            isout = isout || (((unsigned)(ip >> (8 * j)) & 0xFFu) == (unsigned)d);
        if (!isout) p = fma((double)v, (double)pw, p);
    }
#pragma unroll
    for (int off = 1; off < 64; off <<= 1) p += __shfl_xor(p, off);
    if (lane == src) a = (p > 0.0) ? 1.f : -1.f;
    return a;
}

// ---------------- kernel 1: signs + norms + outlier state ----------------
// 256 threads / 4 waves; register-dieted to fit the 64-VGPR occupancy tier
// ((256,4) clamp -> 64 VGPR cap; R2 measured 2x resident waves at this tier).
__global__ __launch_bounds__(256, 4) void qjl_signs(const float* __restrict__ data,
                                                    const float* __restrict__ P,
                                                    const int* __restrict__ oidx,
                                                    const unsigned short* __restrict__ PtHi,
                                                    const unsigned short* __restrict__ PtLo,
                                                    const float* __restrict__ Pt32,
                                                    unsigned long long* __restrict__ wordsg,
                                                    float* __restrict__ sning,
                                                    float* __restrict__ su2g,
                                                    unsigned long long* __restrict__ sidxpg) {
    __shared__ unsigned short abuf[16384];        // 32 KB: hi [0..8191], lo [8192..], XOR-swz
    __shared__ unsigned long long sidxp[TN];
    __shared__ float sfull[TN];
    __shared__ float snout[TN];

    const int tid = threadIdx.x;
    const int lane = tid & 63;
    const int wv = tid >> 6;
    const int l15 = lane & 15;
    const int kgrp = (lane >> 4) << 3;
    const int nt = blockIdx.x, hk = blockIdx.y, b = blockIdx.z;
    const int n0 = nt * TN;
    const size_t rowbase = (size_t)(b * HK_ + hk) * N_ + n0;
    const size_t wblk = (size_t)((b * HK_ + hk) * (N_ / TN) + nt);
    const float* dbase = data + ((size_t)(b * HK_ + hk) * N_) * D_;

    // ---- phase 0: load tile; TRUNCATION hi/lo split (bit-ops only); per-row sumsq ----
    {
        const int r = tid >> 2;
        const int c = tid & 3;
        const float* drow = dbase + (size_t)(n0 + r) * D_;
        const int swz = (r & 7) << 3;
        float ssq = 0.f;
#pragma unroll
        for (int k = 0; k < 8; ++k) {
            const int f = c + 4 * k;
            float4 v = reinterpret_cast<const float4*>(drow)[f];
            ssq += v.x * v.x + v.y * v.y + v.z * v.z + v.w * v.w;
            const unsigned u0 = __float_as_uint(v.x), u1 = __float_as_uint(v.y);
            const unsigned u2 = __float_as_uint(v.z), u3 = __float_as_uint(v.w);
            // hi = truncate to bf16 (mask); lo = f - hi, truncated to bf16
            const unsigned hw0 = (u0 >> 16) | (u1 & 0xFFFF0000u);
            const unsigned hw1 = (u2 >> 16) | (u3 & 0xFFFF0000u);
            const unsigned lu0 = __float_as_uint(v.x - __uint_as_float(u0 & 0xFFFF0000u));
            const unsigned lu1 = __float_as_uint(v.y - __uint_as_float(u1 & 0xFFFF0000u));
            const unsigned lu2 = __float_as_uint(v.z - __uint_as_float(u2 & 0xFFFF0000u));
            const unsigned lu3 = __float_as_uint(v.w - __uint_as_float(u3 & 0xFFFF0000u));
            const unsigned lw0 = (lu0 >> 16) | (lu1 & 0xFFFF0000u);
            const unsigned lw1 = (lu2 >> 16) | (lu3 & 0xFFFF0000u);
            const int ei = r * 128 + ((4 * f) ^ swz);
            *reinterpret_cast<uint2_*>(&abuf[ei]) = (uint2_){hw0, hw1};
            *reinterpret_cast<uint2_*>(&abuf[8192 + ei]) = (uint2_){lw0, lw1};
        }
        ssq += __shfl_xor(ssq, 1);
        ssq += __shfl_xor(ssq, 2);
        if (c == 0) sfull[r] = ssq;
    }
    __syncthreads();

    // ---- phase A: dedup outliers, zero them in LDS, norms; write snin/sidxp out ----
    if (tid < TN) {
        const int n = tid;
        const int* ob = oidx + ((size_t)(b * HK_ + hk) * N_ + n0 + n) * O_;
        const float* drow = dbase + (size_t)(n0 + n) * D_;
        int id[O_];
        int4 i0 = reinterpret_cast<const int4*>(ob)[0];
        int4 i1 = reinterpret_cast<const int4*>(ob)[1];
        id[0] = i0.x; id[1] = i0.y; id[2] = i0.z; id[3] = i0.w;
        id[4] = i1.x; id[5] = i1.y; id[6] = i1.z; id[7] = i1.w;
        const int swz = (n & 7) << 3;
        unsigned long long ip = 0;
        float so2 = 0.f;
#pragma unroll
        for (int j = 0; j < O_; ++j) {
            bool dup = false;
#pragma unroll
            for (int jj = 0; jj < O_; ++jj)
                if (jj < j) dup = dup || (id[jj] == id[j]);
            if (!dup) {
                const float v = drow[id[j]];
                so2 = fmaf(v, v, so2);
                ip |= (unsigned long long)(id[j] & 0xFF) << (8 * j);
                const int ei = n * 128 + (id[j] ^ swz);
                abuf[ei] = 0;
                abuf[8192 + ei] = 0;
            } else {
                ip |= 0xFFull << (8 * j);
            }
        }
        sidxp[n] = ip;
        sidxpg[rowbase + n] = ip;
        const float CIN = (float)(1.2533141373155003 / 256.0);
        const float COUT = (float)(1.2533141373155003 / 64.0);
        sning[rowbase + n] = CIN * sqrtf(fmaxf(sfull[n] - so2, 0.f));
        snout[n] = COUT * sqrtf(so2);
    }
    __syncthreads();

    // ---- phase B: sign_out fp32 + rare exact fp64; float2 chunks, int offsets ----
    {
        const int n = tid >> 2;
        const int c = tid & 3;
        const unsigned long long ip = sidxp[n];
        const float* drow = dbase + (size_t)(n0 + n) * D_;
        int off[O_];
        float u[O_], vv[O_];
#pragma unroll
        for (int j = 0; j < O_; ++j) {
            u[j] = 0.f;
            const unsigned bt = (unsigned)(ip >> (8 * j)) & 0xFFu;
            const int ix = (int)(bt & 0x7Fu);
            off[j] = ix * S_;
            vv[j] = (bt != 0xFFu) ? drow[ix] : 0.f;
        }
#pragma unroll
        for (int ch = 0; ch < 8; ++ch) {
            const int tc = c * 16 + ch * 2;
            float2 pj[O_];
#pragma unroll
            for (int j = 0; j < O_; ++j)
                pj[j] = *reinterpret_cast<const float2*>(P + off[j] + tc);
#pragma unroll
            for (int e = 0; e < 2; ++e) {
                float cs = 0.f;
#pragma unroll
                for (int j = 0; j < O_; ++j)
                    cs = fmaf(vv[j], e ? pj[j].y : pj[j].x, cs);
                float sg;
                if (fabsf(cs) < TAUO) {   // rare exact path
                    double cd = 0.0;
#pragma unroll
                    for (int j = 0; j < O_; ++j)
                        cd = fma((double)vv[j], (double)(e ? pj[j].y : pj[j].x), cd);
                    sg = (cd > 0.0) ? 1.f : ((cd < 0.0) ? -1.f : 0.f);
                } else {
                    sg = (cs > 0.f) ? 1.f : -1.f;
                }
#pragma unroll
                for (int j = 0; j < O_; ++j)
                    u[j] = fmaf(sg, e ? pj[j].y : pj[j].x, u[j]);
            }
        }
#pragma unroll
        for (int j = 0; j < O_; ++j) {
            u[j] += __shfl_xor(u[j], 1);
            u[j] += __shfl_xor(u[j], 2);
        }
        if (c == 0) {
            const float cno = snout[n];
            float o[O_];
#pragma unroll
            for (int j = 0; j < O_; ++j)
                o[j] = (((unsigned)(ip >> (8 * j)) & 0xFFu) != 0xFFu) ? u[j] * cno : 0.f;
            float* sp = su2g + (rowbase + n) * O_;
            *reinterpret_cast<f32x4*>(sp) = (f32x4){o[0], o[1], o[2], o[3]};
            *reinterpret_cast<f32x4*>(sp + 4) = (f32x4){o[4], o[5], o[6], o[7]};
        }
    }
    // no barrier: phase C reads abuf (stable since phase A's barrier)

    // ---- phase C: signs via bf16 hi/lo MFMA; B full per t-tile, A in 2-ks chunks ----
    {
        const int t0 = wv * 4;
#pragma unroll
        for (int ti = 0; ti < 4; ++ti) {
            const int t = t0 + ti;
            short8 bhi[4], blo[4];                // 32 VGPR, loaded once per t
            const size_t bo = (size_t)(16 * t + l15) * D_ + kgrp;
#pragma unroll
            for (int ks = 0; ks < 4; ++ks) {
                bhi[ks] = *reinterpret_cast<const short8*>(PtHi + bo + ks * 32);
                blo[ks] = *reinterpret_cast<const short8*>(PtLo + bo + ks * 32);
            }
#pragma unroll
            for (int rt = 0; rt < 4; ++rt) {
                const int arow = 16 * rt + l15;
                const int aswz = (arow & 7) << 3;
                f32x4 ac1 = (f32x4){0.f, 0.f, 0.f, 0.f};
                f32x4 ac2 = (f32x4){0.f, 0.f, 0.f, 0.f};
#pragma unroll
                for (int kc = 0; kc < 2; ++kc) {
                    short8 ah[2], al[2];           // 16 VGPR A-chunk
#pragma unroll
                    for (int k2 = 0; k2 < 2; ++k2) {
                        const int ks = kc * 2 + k2;
                        const int ei = arow * 128 + ((ks * 32 + kgrp) ^ aswz);
                        ah[k2] = *reinterpret_cast<const short8*>(&abuf[ei]);
                        al[k2] = *reinterpret_cast<const short8*>(&abuf[8192 + ei]);
                    }
#pragma unroll
                    for (int k2 = 0; k2 < 2; ++k2) {
                        const int ks = kc * 2 + k2;
                        ac1 = __builtin_amdgcn_mfma_f32_16x16x32_bf16(ah[k2], bhi[ks], ac1, 0, 0, 0);
                        ac2 = __builtin_amdgcn_mfma_f32_16x16x32_bf16(ah[k2], blo[ks], ac2, 0, 0, 0);
                        ac2 = __builtin_amdgcn_mfma_f32_16x16x32_bf16(al[k2], bhi[ks], ac2, 0, 0, 0);
                    }
                }
                f32x4 a = ac1 + ac2;
                const float mn = fminf(fminf(fabsf(a[0]), fabsf(a[1])),
                                       fminf(fabsf(a[2]), fabsf(a[3])));
                if (__ballot(mn < TAU) != 0ull) {   // rare
#pragma unroll
                    for (int r = 0; r < 4; ++r) {
                        unsigned long long low = __ballot(fabsf(a[r]) < TAU);
                        while (low) {
                            const int src = __ffsll((unsigned long long)low) - 1;
                            low &= low - 1;
                            const int row = 16 * rt + ((src >> 4) << 2) + r;
                            const int col = 16 * t + (src & 15);
                            a[r] = qjl_fix_coop(dbase + (size_t)(n0 + row) * D_, Pt32, col,
                                                sidxp[row], a[r], src);
                        }
                    }
                }
                unsigned long long bb0 = __ballot(a[0] > 0.f);
                unsigned long long bb1 = __ballot(a[1] > 0.f);
                unsigned long long bb2 = __ballot(a[2] > 0.f);
                unsigned long long bb3 = __ballot(a[3] > 0.f);
                if (lane == 0) {
                    unsigned long long* wp = wordsg + (wblk * 256 + (size_t)(rt * 16 + t) * 4);
                    *reinterpret_cast<ull2*>(wp) = (ull2){bb0, bb1};
                    *reinterpret_cast<ull2*>(wp + 2) = (ull2){bb2, bb3};
                }
            }
        }
    }
}

// ---------------- kernel 2: expand signs + output GEMM (256 threads / 4 waves) ----
__global__ __launch_bounds__(256, 4) void qjl_out(const unsigned short* __restrict__ sqHi,
                                                  const float* __restrict__ qT,
                                                  const unsigned long long* __restrict__ wordsg,
                                                  const float* __restrict__ sning,
                                                  const float* __restrict__ su2g,
                                                  const unsigned long long* __restrict__ sidxpg,
                                                  float* __restrict__ out) {
    __shared__ unsigned short scol[16384];       // 32 KB: [n][256] bf16 = +/- cni, XOR-swz

    const int tid = threadIdx.x;
    const int lane = tid & 63;
    const int wv = tid >> 6;
    const int l15 = lane & 15;
    const int kgrp = (lane >> 4) << 3;
    const int nt = blockIdx.x, hk = blockIdx.y, b = blockIdx.z;
    const int n0 = nt * TN;
    const size_t rowbase = (size_t)(b * HK_ + hk) * N_ + n0;
    const size_t wblk = (size_t)((b * HK_ + hk) * (N_ / TN) + nt);
    const int hq = hk * G_ + wv;

    // A-fragment prefetch (latency hidden under expansion)
    const unsigned short* sqb = sqHi + (size_t)(b * HQ_ + hq) * (M_ * S_);
    short8 aq[8];
#pragma unroll
    for (int ks = 0; ks < 8; ++ks)
        aq[ks] = *reinterpret_cast<const short8*>(sqb + (size_t)l15 * S_ + ks * 32 + kgrp);

    // ---- expansion: scol[n][s] = (sign ? +1 : -1) * bf16(cni[n]) ----
    {
        const int n = tid & 63;
        const int c64 = tid >> 6;
        const unsigned short cb = f2bf_rne(sning[rowbase + n]);
        const unsigned base = (unsigned)cb | ((unsigned)cb << 16);
        const int g = (n >> 2) & 3;
        const int r = n & 3;
        const int w = n >> 4;
        const int swz = (n & 7) << 3;
        const unsigned long long* wbp = wordsg + wblk * 256;
#pragma unroll
        for (int i = 0; i < 4; ++i) {
            const int t = c64 * 4 + i;
            const unsigned long long wd = wbp[(size_t)(w * 16 + t) * 4 + r];
            const unsigned bits = (unsigned)(wd >> (16 * g)) & 0xFFFFu;
            const unsigned nb = ~bits;
            unsigned o[8];
#pragma unroll
            for (int p = 0; p < 8; ++p) {
                const unsigned m = (((nb >> (2 * p)) & 1u) << 15) |
                                   (((nb >> (2 * p + 1)) & 1u) << 31);
                o[p] = base ^ m;
            }
            const int s0 = c64 * 64 + i * 16;
            const int e0 = n * 256 + (s0 ^ swz);
            const int e1 = n * 256 + ((s0 + 8) ^ swz);
            *reinterpret_cast<uint4_*>(&scol[e0]) = (uint4_){o[0], o[1], o[2], o[3]};
            *reinterpret_cast<uint4_*>(&scol[e1]) = (uint4_){o[4], o[5], o[6], o[7]};
        }
    }
    __syncthreads();

    // ---- GEMM + sparse part2 per wave/head ----
    {
        const float* qtb = qT + (size_t)(b * HQ_ + hq) * (D_ * M_);
        const int m0 = (lane >> 4) << 2;
#pragma unroll
        for (int ct = 0; ct < 4; ++ct) {
            const int n = 16 * ct + l15;
            const size_t row = rowbase + n;
            const unsigned long long ip = sidxpg[row];
            const f32x4 s01 = *reinterpret_cast<const f32x4*>(su2g + row * O_);
            const f32x4 s23 = *reinterpret_cast<const f32x4*>(su2g + row * O_ + 4);
            const int nswz = (n & 7) << 3;
            f32x4 acc = (f32x4){0.f, 0.f, 0.f, 0.f};
#pragma unroll
            for (int ks = 0; ks < 8; ++ks) {
                const int ei = n * 256 + ((ks * 32 + kgrp) ^ nswz);
                const short8 bs = *reinterpret_cast<const short8*>(&scol[ei]);
                acc = __builtin_amdgcn_mfma_f32_16x16x32_bf16(aq[ks], bs, acc, 0, 0, 0);
            }
            float a0 = 0.f, a1 = 0.f, a2 = 0.f, a3 = 0.f;
#pragma unroll
            for (int j = 0; j < O_; ++j) {
                const float uj = (j < 4) ? s01[j & 3] : s23[j & 3];
                const int ix = (int)((ip >> (8 * j)) & 0x7Fu);
                const float4 qv = *reinterpret_cast<const float4*>(qtb + ix * M_ + m0);
                a0 = fmaf(uj, qv.x, a0);
                a1 = fmaf(uj, qv.y, a1);
                a2 = fmaf(uj, qv.z, a2);
                a3 = fmaf(uj, qv.w, a3);
            }
            acc[0] += a0; acc[1] += a1; acc[2] += a2; acc[3] += a3;
            float* ob = out + ((size_t)(b * HQ_ + hq) * N_ + (n0 + n)) * M_ + m0;
            *reinterpret_cast<f32x4*>(ob) = acc;
        }
    }
}

extern "C" void kernel_launch(void* const* d_in, const int* in_sizes, int n_in,
                              void* d_out, int out_size, void* d_ws, size_t ws_size,
                              hipStream_t stream) {
    const float* query = (const float*)d_in[0];  // [B][HQ][M][D]
    const float* data  = (const float*)d_in[1];  // [B][HK][N][D]
    const float* proj  = (const float*)d_in[2];  // [D][S]
    const int*   oidx  = (const int*)d_in[3];    // [B][HK][N][O]

    float* out = (float*)d_out;                  // [B][HQ][N][M]

    char* ws = (char*)d_ws;
    unsigned short* sqHi  = (unsigned short*)(ws);                     // 1 MB
    float*          qT    = (float*)(ws + (1 << 20));                  // 1 MB
    unsigned short* PtHi  = (unsigned short*)(ws + (2 << 20));         // 64 KB
    unsigned short* PtLo  = (unsigned short*)(ws + (2 << 20) + (64 << 10));   // 64 KB
    float*          Pt32  = (float*)(ws + (2 << 20) + (128 << 10));    // 128 KB
    unsigned long long* wordsg = (unsigned long long*)(ws + (3 << 20)); // 8 MB
    float*          sning = (float*)(ws + (11 << 20));                 // 1 MB
    float*          su2g  = (float*)(ws + (12 << 20));                 // 8 MB
    unsigned long long* sidxpg = (unsigned long long*)(ws + (20 << 20)); // 2 MB

    qjl_prept<<<dim3(D_), dim3(S_), 0, stream>>>(proj, PtHi, PtLo, Pt32);
    qjl_sketch_q<<<dim3(B_ * HQ_), dim3(256), 0, stream>>>(query, proj, sqHi, qT);
    qjl_signs<<<dim3(N_ / TN, HK_, B_), dim3(256), 0, stream>>>(
        data, proj, oidx, PtHi, PtLo, Pt32, wordsg, sning, su2g, sidxpg);
    qjl_out<<<dim3(N_ / TN, HK_, B_), dim3(256), 0, stream>>>(
        sqHi, qT, wordsg, sning, su2g, sidxpg, out);
}

// Round 10
// 336.122 us; speedup vs baseline: 1.3455x; 1.3455x over previous
//
#include <hip/hip_runtime.h>
#include <hip/hip_bf16.h>
#include <math.h>

namespace {
constexpr int B_ = 4, HQ_ = 32, HK_ = 8, G_ = 4, M_ = 16;
constexpr int N_ = 8192, D_ = 128, S_ = 256, O_ = 8;
constexpr int TN = 64;               // n-rows per block
constexpr float TAU  = 1e-3f;        // inlier sign: |I| below -> exact fp64 recheck
constexpr float TAUO = 2e-4f;        // outlier sign: |F-I| below -> exact fp64 recheck
}

typedef short short8 __attribute__((ext_vector_type(8)));
typedef float f32x4 __attribute__((ext_vector_type(4)));
typedef unsigned int uint4_ __attribute__((ext_vector_type(4)));
typedef unsigned int uint2_ __attribute__((ext_vector_type(2)));
typedef unsigned long long ull2 __attribute__((ext_vector_type(2)));

__device__ inline unsigned short f2bf_rne(float f) {
    unsigned u = __float_as_uint(f);
    u += 0x7FFF + ((u >> 16) & 1);
    return (unsigned short)(u >> 16);
}
__device__ inline float bf2f(unsigned short h) {
    return __uint_as_float(((unsigned)h) << 16);
}

// ---- prept: PtHi/PtLo[s][d], PdHi/PdLo[d][s] = bf16 hi/lo of P; Pt32[s][d] fp32 ----
__global__ __launch_bounds__(256) void qjl_prept(const float* __restrict__ P,
                                                 unsigned short* __restrict__ PtHi,
                                                 unsigned short* __restrict__ PtLo,
                                                 unsigned short* __restrict__ PdHi,
                                                 unsigned short* __restrict__ PdLo,
                                                 float* __restrict__ Pt32) {
    const int d = blockIdx.x;      // 0..127
    const int s = threadIdx.x;     // 0..255
    const float f = P[d * S_ + s];
    const unsigned short hb = f2bf_rne(f);
    const float lof = f - bf2f(hb);
    const unsigned short lb = f2bf_rne(lof);
    PtHi[s * D_ + d] = hb;
    PtLo[s * D_ + d] = lb;
    PdHi[d * S_ + s] = hb;
    PdLo[d * S_ + s] = lb;
    Pt32[s * D_ + d] = f;
}

// ---- kernel A: sqHi[head][m][s] = bf16(q · P); qT[head][d][m] = q^T ----
__global__ __launch_bounds__(256) void qjl_sketch_q(const float* __restrict__ q,
                                                    const float* __restrict__ P,
                                                    unsigned short* __restrict__ sqHi,
                                                    float* __restrict__ qT) {
    __shared__ float qs[M_][D_];
    const int tid = threadIdx.x;
    const size_t blk = blockIdx.x;  // b*HQ + hq
    const float* qb = q + blk * (size_t)(M_ * D_);
    for (int i = tid; i < M_ * D_ / 4; i += 256)
        reinterpret_cast<float4*>(&qs[0][0])[i] = reinterpret_cast<const float4*>(qb)[i];
    __syncthreads();
    float* qtb = qT + blk * (size_t)(D_ * M_);
    for (int i = tid; i < D_ * M_ / 4; i += 256) {
        const int d = i >> 2;
        const int m4 = i & 3;
        float4 v;
        v.x = qs[m4 * 4 + 0][d];
        v.y = qs[m4 * 4 + 1][d];
        v.z = qs[m4 * 4 + 2][d];
        v.w = qs[m4 * 4 + 3][d];
        reinterpret_cast<float4*>(qtb)[i] = v;
    }
    float acc[M_];
#pragma unroll
    for (int m = 0; m < M_; ++m) acc[m] = 0.f;
    const int s = tid;
    for (int d = 0; d < D_; ++d) {
        const float pv = P[d * S_ + s];
#pragma unroll
        for (int m = 0; m < M_; ++m) acc[m] = fmaf(qs[m][d], pv, acc[m]);
    }
    unsigned short* ob = sqHi + blk * (size_t)(M_ * S_);
#pragma unroll
    for (int m = 0; m < M_; ++m) ob[m * S_ + s] = f2bf_rne(acc[m]);
}

// rare cooperative path: exact fp64 sign of k_in[row] . P[:,col]; whole wave participates.
__device__ __noinline__ float qjl_fix_coop(const float* __restrict__ drow,
                                           const float* __restrict__ Pt32,
                                           int col, unsigned long long ip,
                                           float a, int src) {
    const int lane = threadIdx.x & 63;
    const float2 dv = *reinterpret_cast<const float2*>(&drow[2 * lane]);
    const float2 pv = *reinterpret_cast<const float2*>(&Pt32[(size_t)col * D_ + 2 * lane]);
    double p = 0.0;
#pragma unroll
    for (int e = 0; e < 2; ++e) {
        const int d = 2 * lane + e;
        const float v = e ? dv.y : dv.x;
        const float pw = e ? pv.y : pv.x;
        bool isout = false;
#pragma unroll
        for (int j = 0; j < 8; ++j)
            isout = isout || (((unsigned)(ip >> (8 * j)) & 0xFFu) == (unsigned)d);
        if (!isout) p = fma((double)v, (double)pw, p);
    }
#pragma unroll
    for (int off = 1; off < 64; off <<= 1) p += __shfl_xor(p, off);
    if (lane == src) a = (p > 0.0) ? 1.f : -1.f;
    return a;
}

// ---------------- kernel 1: signs + norms + outlier state (gather-free) ----------------
// Phases: P0 load/split | PF F=full.P (t<64) | PA dedup/zero | PC I=k_in.P + Dt=F-I |
//         PE expand sign_out | PY y=sg.Pd^T (MFMA) | PU su2 extraction.
__global__ __launch_bounds__(256) void qjl_signs(const float* __restrict__ data,
                                                 const float* __restrict__ P,
                                                 const int* __restrict__ oidx,
                                                 const unsigned short* __restrict__ PtHi,
                                                 const unsigned short* __restrict__ PtLo,
                                                 const unsigned short* __restrict__ PdHi,
                                                 const unsigned short* __restrict__ PdLo,
                                                 const float* __restrict__ Pt32,
                                                 unsigned long long* __restrict__ wordsg,
                                                 float* __restrict__ sning,
                                                 float* __restrict__ su2g,
                                                 unsigned long long* __restrict__ sidxpg) {
    __shared__ unsigned short abuf[16384];   // 32KB: hi [0..8191], lo [8192..]; later ybuf
    __shared__ float fbufT[4096];            // 16KB: F^T [t][n] fp32; later sgmat (8KB)
    __shared__ unsigned long long sgw[64];   // sign_out ballot words [(rt*4+t)*4+r]
    __shared__ unsigned long long sidxp[TN];
    __shared__ float sfull[TN];
    __shared__ float snout[TN];

    float* ybuf = reinterpret_cast<float*>(abuf);              // alias (post-PC)
    unsigned short* sgmat = reinterpret_cast<unsigned short*>(fbufT);  // alias (post-PC)

    const int tid = threadIdx.x;
    const int lane = tid & 63;
    const int wv = tid >> 6;
    const int l15 = lane & 15;
    const int kgrp = (lane >> 4) << 3;
    const int nt = blockIdx.x, hk = blockIdx.y, b = blockIdx.z;
    const int n0 = nt * TN;
    const size_t rowbase = (size_t)(b * HK_ + hk) * N_ + n0;
    const size_t wblk = (size_t)((b * HK_ + hk) * (N_ / TN) + nt);
    const float* dbase = data + ((size_t)(b * HK_ + hk) * N_) * D_;

    // ---- P0: load tile; truncation hi/lo split into abuf (no zeroing); sumsq ----
    {
        const int r = tid >> 2;
        const int c = tid & 3;
        const float* drow = dbase + (size_t)(n0 + r) * D_;
        const int swz = (r & 7) << 3;
        float ssq = 0.f;
#pragma unroll
        for (int k = 0; k < 8; ++k) {
            const int f = c + 4 * k;
            float4 v = reinterpret_cast<const float4*>(drow)[f];
            ssq += v.x * v.x + v.y * v.y + v.z * v.z + v.w * v.w;
            const unsigned u0 = __float_as_uint(v.x), u1 = __float_as_uint(v.y);
            const unsigned u2 = __float_as_uint(v.z), u3 = __float_as_uint(v.w);
            const unsigned hw0 = (u0 >> 16) | (u1 & 0xFFFF0000u);
            const unsigned hw1 = (u2 >> 16) | (u3 & 0xFFFF0000u);
            const unsigned lu0 = __float_as_uint(v.x - __uint_as_float(u0 & 0xFFFF0000u));
            const unsigned lu1 = __float_as_uint(v.y - __uint_as_float(u1 & 0xFFFF0000u));
            const unsigned lu2 = __float_as_uint(v.z - __uint_as_float(u2 & 0xFFFF0000u));
            const unsigned lu3 = __float_as_uint(v.w - __uint_as_float(u3 & 0xFFFF0000u));
            const unsigned lw0 = (lu0 >> 16) | (lu1 & 0xFFFF0000u);
            const unsigned lw1 = (lu2 >> 16) | (lu3 & 0xFFFF0000u);
            const int ei = r * 128 + ((4 * f) ^ swz);
            *reinterpret_cast<uint2_*>(&abuf[ei]) = (uint2_){hw0, hw1};
            *reinterpret_cast<uint2_*>(&abuf[8192 + ei]) = (uint2_){lw0, lw1};
        }
        ssq += __shfl_xor(ssq, 1);
        ssq += __shfl_xor(ssq, 2);
        if (c == 0) sfull[r] = ssq;
    }

    // PF B-frags (pure global; issued before barrier to hide L2 latency)
    short8 bhiF[4], bloF[4];
    {
        const size_t bo = (size_t)(16 * wv + l15) * D_ + kgrp;
#pragma unroll
        for (int ks = 0; ks < 4; ++ks) {
            bhiF[ks] = *reinterpret_cast<const short8*>(PtHi + bo + ks * 32);
            bloF[ks] = *reinterpret_cast<const short8*>(PtLo + bo + ks * 32);
        }
    }
    __syncthreads();

    // ---- PF: F = full . P for t-tile wv  -> fbufT[t][n] (XOR-swz on n-quad) ----
    {
#pragma unroll
        for (int rt = 0; rt < 4; ++rt) {
            const int arow = 16 * rt + l15;
            const int aswz = (arow & 7) << 3;
            short8 ahi[4], alo[4];
#pragma unroll
            for (int ks = 0; ks < 4; ++ks) {
                const int ei = arow * 128 + ((ks * 32 + kgrp) ^ aswz);
                ahi[ks] = *reinterpret_cast<const short8*>(&abuf[ei]);
                alo[ks] = *reinterpret_cast<const short8*>(&abuf[8192 + ei]);
            }
            f32x4 ac1 = (f32x4){0.f, 0.f, 0.f, 0.f};
            f32x4 ac2 = (f32x4){0.f, 0.f, 0.f, 0.f};
            f32x4 ac3 = (f32x4){0.f, 0.f, 0.f, 0.f};
#pragma unroll
            for (int ks = 0; ks < 4; ++ks) {
                ac1 = __builtin_amdgcn_mfma_f32_16x16x32_bf16(ahi[ks], bhiF[ks], ac1, 0, 0, 0);
                ac2 = __builtin_amdgcn_mfma_f32_16x16x32_bf16(ahi[ks], bloF[ks], ac2, 0, 0, 0);
                ac3 = __builtin_amdgcn_mfma_f32_16x16x32_bf16(alo[ks], bhiF[ks], ac3, 0, 0, 0);
            }
            f32x4 a = (ac1 + ac2) + ac3;
            const int colt = 16 * wv + l15;
            const int nq = 16 * rt + ((lane >> 4) << 2);
            *reinterpret_cast<f32x4*>(&fbufT[colt * 64 + (nq ^ ((colt & 7) << 2))]) = a;
        }
    }
    __syncthreads();

    // ---- PA: dedup outliers, zero abuf, norms; write snin/sidxp out ----
    if (tid < TN) {
        const int n = tid;
        const int* ob = oidx + ((size_t)(b * HK_ + hk) * N_ + n0 + n) * O_;
        const float* drow = dbase + (size_t)(n0 + n) * D_;
        int id[O_];
        int4 i0 = reinterpret_cast<const int4*>(ob)[0];
        int4 i1 = reinterpret_cast<const int4*>(ob)[1];
        id[0] = i0.x; id[1] = i0.y; id[2] = i0.z; id[3] = i0.w;
        id[4] = i1.x; id[5] = i1.y; id[6] = i1.z; id[7] = i1.w;
        const int swz = (n & 7) << 3;
        unsigned long long ip = 0;
        float so2 = 0.f;
#pragma unroll
        for (int j = 0; j < O_; ++j) {
            bool dup = false;
#pragma unroll
            for (int jj = 0; jj < O_; ++jj)
                if (jj < j) dup = dup || (id[jj] == id[j]);
            if (!dup) {
                const float v = drow[id[j]];
                so2 = fmaf(v, v, so2);
                ip |= (unsigned long long)(id[j] & 0xFF) << (8 * j);
                const int ei = n * 128 + (id[j] ^ swz);
                abuf[ei] = 0;
                abuf[8192 + ei] = 0;
            } else {
                ip |= 0xFFull << (8 * j);
            }
        }
        sidxp[n] = ip;
        sidxpg[rowbase + n] = ip;
        const float CIN = (float)(1.2533141373155003 / 256.0);
        const float COUT = (float)(1.2533141373155003 / 64.0);
        sning[rowbase + n] = CIN * sqrtf(fmaxf(sfull[n] - so2, 0.f));
        snout[n] = COUT * sqrtf(so2);
    }
    __syncthreads();

    // ---- PC: I = k_in . P (all 256 cols); wave 0 also Dt = F - I -> sign_out ----
    {
        const int t0 = wv * 4;
#pragma unroll
        for (int ti = 0; ti < 4; ++ti) {
            const int t = t0 + ti;
            short8 bhi[4], blo[4];
            const size_t bo = (size_t)(16 * t + l15) * D_ + kgrp;
#pragma unroll
            for (int ks = 0; ks < 4; ++ks) {
                bhi[ks] = *reinterpret_cast<const short8*>(PtHi + bo + ks * 32);
                blo[ks] = *reinterpret_cast<const short8*>(PtLo + bo + ks * 32);
            }
#pragma unroll
            for (int rt = 0; rt < 4; ++rt) {
                const int arow = 16 * rt + l15;
                const int aswz = (arow & 7) << 3;
                short8 ahi[4], alo[4];
#pragma unroll
                for (int ks = 0; ks < 4; ++ks) {
                    const int ei = arow * 128 + ((ks * 32 + kgrp) ^ aswz);
                    ahi[ks] = *reinterpret_cast<const short8*>(&abuf[ei]);
                    alo[ks] = *reinterpret_cast<const short8*>(&abuf[8192 + ei]);
                }
                f32x4 ac1 = (f32x4){0.f, 0.f, 0.f, 0.f};
                f32x4 ac2 = (f32x4){0.f, 0.f, 0.f, 0.f};
                f32x4 ac3 = (f32x4){0.f, 0.f, 0.f, 0.f};
#pragma unroll
                for (int ks = 0; ks < 4; ++ks) {
                    ac1 = __builtin_amdgcn_mfma_f32_16x16x32_bf16(ahi[ks], bhi[ks], ac1, 0, 0, 0);
                    ac2 = __builtin_amdgcn_mfma_f32_16x16x32_bf16(ahi[ks], blo[ks], ac2, 0, 0, 0);
                    ac3 = __builtin_amdgcn_mfma_f32_16x16x32_bf16(alo[ks], bhi[ks], ac3, 0, 0, 0);
                }
                f32x4 a = (ac1 + ac2) + ac3;

                if (wv == 0) {
                    // Dt = F - I (raw I, before sign-fixup); sign_out for cols 16t+l15
                    const int colt = 16 * t + l15;
                    const int nq = 16 * rt + ((lane >> 4) << 2);
                    const f32x4 fv = *reinterpret_cast<const f32x4*>(
                        &fbufT[colt * 64 + (nq ^ ((colt & 7) << 2))]);
                    f32x4 dt = fv - a;
                    const float mno = fminf(fminf(fabsf(dt[0]), fabsf(dt[1])),
                                            fminf(fabsf(dt[2]), fabsf(dt[3])));
                    if (__ballot(mno < TAUO) != 0ull) {   // rare per-lane exact path
#pragma unroll
                        for (int r = 0; r < 4; ++r) {
                            if (fabsf(dt[r]) < TAUO) {
                                const int row = nq + r;
                                const unsigned long long ip2 = sidxp[row];
                                const float* drow2 = dbase + (size_t)(n0 + row) * D_;
                                double pd = 0.0;
#pragma unroll
                                for (int j = 0; j < O_; ++j) {
                                    const unsigned bt = (unsigned)(ip2 >> (8 * j)) & 0xFFu;
                                    if (bt != 0xFFu) {
                                        const int dd = (int)(bt & 0x7Fu);
                                        pd = fma((double)drow2[dd],
                                                 (double)P[(size_t)dd * S_ + colt], pd);
                                    }
                                }
                                dt[r] = (pd > 0.0) ? 1.f : -1.f;
                            }
                        }
                    }
#pragma unroll
                    for (int r = 0; r < 4; ++r) {
                        const unsigned long long bbo = __ballot(dt[r] > 0.f);
                        if (lane == 0) sgw[(rt * 4 + t) * 4 + r] = bbo;
                    }
                }

                const float mn = fminf(fminf(fabsf(a[0]), fabsf(a[1])),
                                       fminf(fabsf(a[2]), fabsf(a[3])));
                if (__ballot(mn < TAU) != 0ull) {   // rare coop exact path
#pragma unroll
                    for (int r = 0; r < 4; ++r) {
                        unsigned long long low = __ballot(fabsf(a[r]) < TAU);
                        while (low) {
                            const int src = __ffsll((unsigned long long)low) - 1;
                            low &= low - 1;
                            const int row = 16 * rt + ((src >> 4) << 2) + r;
                            const int col = 16 * t + (src & 15);
                            a[r] = qjl_fix_coop(dbase + (size_t)(n0 + row) * D_, Pt32, col,
                                                sidxp[row], a[r], src);
                        }
                    }
                }
                unsigned long long bb0 = __ballot(a[0] > 0.f);
                unsigned long long bb1 = __ballot(a[1] > 0.f);
                unsigned long long bb2 = __ballot(a[2] > 0.f);
                unsigned long long bb3 = __ballot(a[3] > 0.f);
                if (lane == 0) {
                    unsigned long long* wp = wordsg + (wblk * 256 + (size_t)(rt * 16 + t) * 4);
                    *reinterpret_cast<ull2*>(wp) = (ull2){bb0, bb1};
                    *reinterpret_cast<ull2*>(wp + 2) = (ull2){bb2, bb3};
                }
            }
        }
    }
    __syncthreads();

    // ---- PE: expand sgw -> sgmat[n][t] bf16 +/-1 (XOR-swz, overwrites fbufT) ----
    {
        const int n = tid & 63;
        const int ti = tid >> 6;               // 0..3
        const unsigned long long wd = sgw[((n >> 4) * 4 + ti) * 4 + (n & 3)];
        const unsigned bits = (unsigned)(wd >> (16 * ((n >> 2) & 3))) & 0xFFFFu;
        unsigned o[8];
#pragma unroll
        for (int p = 0; p < 8; ++p) {
            const unsigned s0 = (bits >> (2 * p)) & 1u;
            const unsigned s1 = (bits >> (2 * p + 1)) & 1u;
            o[p] = (s0 ? 0x3F80u : 0xBF80u) | ((s1 ? 0x3F80u : 0xBF80u) << 16);
        }
        const int sw = (n & 7) << 3;
        const int t0 = 16 * ti;
        *reinterpret_cast<uint4_*>(&sgmat[n * 64 + (t0 ^ sw)]) =
            (uint4_){o[0], o[1], o[2], o[3]};
        *reinterpret_cast<uint4_*>(&sgmat[n * 64 + ((t0 + 8) ^ sw)]) =
            (uint4_){o[4], o[5], o[6], o[7]};
    }
    __syncthreads();

    // ---- PY: y[n][d] = sum_t sg[n][t] * P[d][t]  via MFMA; ybuf overwrites abuf ----
    {
        f32x4 acc[2][4];
#pragma unroll
        for (int dti = 0; dti < 2; ++dti)
#pragma unroll
            for (int ntl = 0; ntl < 4; ++ntl) acc[dti][ntl] = (f32x4){0.f, 0.f, 0.f, 0.f};
#pragma unroll
        for (int kc = 0; kc < 2; ++kc) {
            short8 bs[4];
#pragma unroll
            for (int ntl = 0; ntl < 4; ++ntl) {
                const int n = 16 * ntl + l15;
                bs[ntl] = *reinterpret_cast<const short8*>(
                    &sgmat[n * 64 + ((kc * 32 + kgrp) ^ ((n & 7) << 3))]);
            }
#pragma unroll
            for (int dti = 0; dti < 2; ++dti) {
                const int drow = 16 * (2 * wv + dti) + l15;
                const size_t ao = (size_t)drow * S_ + kc * 32 + kgrp;
                const short8 ah = *reinterpret_cast<const short8*>(PdHi + ao);
                const short8 al = *reinterpret_cast<const short8*>(PdLo + ao);
#pragma unroll
                for (int ntl = 0; ntl < 4; ++ntl) {
                    acc[dti][ntl] = __builtin_amdgcn_mfma_f32_16x16x32_bf16(ah, bs[ntl], acc[dti][ntl], 0, 0, 0);
                    acc[dti][ntl] = __builtin_amdgcn_mfma_f32_16x16x32_bf16(al, bs[ntl], acc[dti][ntl], 0, 0, 0);
                }
            }
        }
#pragma unroll
        for (int dti = 0; dti < 2; ++dti)
#pragma unroll
            for (int ntl = 0; ntl < 4; ++ntl) {
                const int n = 16 * ntl + l15;
                const int d0 = 16 * (2 * wv + dti) + ((lane >> 4) << 2);
                *reinterpret_cast<f32x4*>(&ybuf[n * 128 + (d0 ^ ((n & 7) << 2))]) =
                    acc[dti][ntl];
            }
    }
    __syncthreads();

    // ---- PU: su2[n][j] = cno * y[n][d_j] ----
    if (tid < TN) {
        const int n = tid;
        const unsigned long long ip = sidxp[n];
        const float cno = snout[n];
        const int sw = (n & 7) << 2;
        float o[O_];
#pragma unroll
        for (int j = 0; j < O_; ++j) {
            const unsigned bt = (unsigned)(ip >> (8 * j)) & 0xFFu;
            const int dd = (int)(bt & 0x7Fu);
            const float y = ybuf[n * 128 + (dd ^ sw)];
            o[j] = (bt != 0xFFu) ? y * cno : 0.f;
        }
        float* sp = su2g + (rowbase + n) * O_;
        *reinterpret_cast<f32x4*>(sp) = (f32x4){o[0], o[1], o[2], o[3]};
        *reinterpret_cast<f32x4*>(sp + 4) = (f32x4){o[4], o[5], o[6], o[7]};
    }
}

// ---------------- kernel 2: expand signs + output GEMM (64-VGPR tier, no spills) ----
__global__ __launch_bounds__(256, 4) void qjl_out(const unsigned short* __restrict__ sqHi,
                                                  const float* __restrict__ qT,
                                                  const unsigned long long* __restrict__ wordsg,
                                                  const float* __restrict__ sning,
                                                  const float* __restrict__ su2g,
                                                  const unsigned long long* __restrict__ sidxpg,
                                                  float* __restrict__ out) {
    __shared__ unsigned short scol[16384];       // 32 KB: [n][256] bf16 = +/- cni, XOR-swz

    const int tid = threadIdx.x;
    const int lane = tid & 63;
    const int wv = tid >> 6;
    const int l15 = lane & 15;
    const int kgrp = (lane >> 4) << 3;
    const int nt = blockIdx.x, hk = blockIdx.y, b = blockIdx.z;
    const int n0 = nt * TN;
    const size_t rowbase = (size_t)(b * HK_ + hk) * N_ + n0;
    const size_t wblk = (size_t)((b * HK_ + hk) * (N_ / TN) + nt);
    const int hq = hk * G_ + wv;

    const unsigned short* sqb = sqHi + (size_t)(b * HQ_ + hq) * (M_ * S_);
    short8 aq[8];
#pragma unroll
    for (int ks = 0; ks < 8; ++ks)
        aq[ks] = *reinterpret_cast<const short8*>(sqb + (size_t)l15 * S_ + ks * 32 + kgrp);

    {
        const int n = tid & 63;
        const int c64 = tid >> 6;
        const unsigned short cb = f2bf_rne(sning[rowbase + n]);
        const unsigned base = (unsigned)cb | ((unsigned)cb << 16);
        const int g = (n >> 2) & 3;
        const int r = n & 3;
        const int w = n >> 4;
        const int swz = (n & 7) << 3;
        const unsigned long long* wbp = wordsg + wblk * 256;
#pragma unroll
        for (int i = 0; i < 4; ++i) {
            const int t = c64 * 4 + i;
            const unsigned long long wd = wbp[(size_t)(w * 16 + t) * 4 + r];
            const unsigned bits = (unsigned)(wd >> (16 * g)) & 0xFFFFu;
            const unsigned nb = ~bits;
            unsigned o[8];
#pragma unroll
            for (int p = 0; p < 8; ++p) {
                const unsigned m = (((nb >> (2 * p)) & 1u) << 15) |
                                   (((nb >> (2 * p + 1)) & 1u) << 31);
                o[p] = base ^ m;
            }
            const int s0 = c64 * 64 + i * 16;
            const int e0 = n * 256 + (s0 ^ swz);
            const int e1 = n * 256 + ((s0 + 8) ^ swz);
            *reinterpret_cast<uint4_*>(&scol[e0]) = (uint4_){o[0], o[1], o[2], o[3]};
            *reinterpret_cast<uint4_*>(&scol[e1]) = (uint4_){o[4], o[5], o[6], o[7]};
        }
    }
    __syncthreads();

    {
        const float* qtb = qT + (size_t)(b * HQ_ + hq) * (D_ * M_);
        const int m0 = (lane >> 4) << 2;
#pragma unroll
        for (int ct = 0; ct < 4; ++ct) {
            const int n = 16 * ct + l15;
            const size_t row = rowbase + n;
            const unsigned long long ip = sidxpg[row];
            const f32x4 s01 = *reinterpret_cast<const f32x4*>(su2g + row * O_);
            const f32x4 s23 = *reinterpret_cast<const f32x4*>(su2g + row * O_ + 4);
            const int nswz = (n & 7) << 3;
            f32x4 acc = (f32x4){0.f, 0.f, 0.f, 0.f};
#pragma unroll
            for (int ks = 0; ks < 8; ++ks) {
                const int ei = n * 256 + ((ks * 32 + kgrp) ^ nswz);
                const short8 bs = *reinterpret_cast<const short8*>(&scol[ei]);
                acc = __builtin_amdgcn_mfma_f32_16x16x32_bf16(aq[ks], bs, acc, 0, 0, 0);
            }
            float a0 = 0.f, a1 = 0.f, a2 = 0.f, a3 = 0.f;
#pragma unroll
            for (int j = 0; j < O_; ++j) {
                const float uj = (j < 4) ? s01[j & 3] : s23[j & 3];
                const int ix = (int)((ip >> (8 * j)) & 0x7Fu);
                const float4 qv = *reinterpret_cast<const float4*>(qtb + ix * M_ + m0);
                a0 = fmaf(uj, qv.x, a0);
                a1 = fmaf(uj, qv.y, a1);
                a2 = fmaf(uj, qv.z, a2);
                a3 = fmaf(uj, qv.w, a3);
            }
            acc[0] += a0; acc[1] += a1; acc[2] += a2; acc[3] += a3;
            float* ob = out + ((size_t)(b * HQ_ + hq) * N_ + (n0 + n)) * M_ + m0;
            *reinterpret_cast<f32x4*>(ob) = acc;
        }
    }
}

extern "C" void kernel_launch(void* const* d_in, const int* in_sizes, int n_in,
                              void* d_out, int out_size, void* d_ws, size_t ws_size,
                              hipStream_t stream) {
    const float* query = (const float*)d_in[0];  // [B][HQ][M][D]
    const float* data  = (const float*)d_in[1];  // [B][HK][N][D]
    const float* proj  = (const float*)d_in[2];  // [D][S]
    const int*   oidx  = (const int*)d_in[3];    // [B][HK][N][O]

    float* out = (float*)d_out;                  // [B][HQ][N][M]

    char* ws = (char*)d_ws;
    unsigned short* sqHi  = (unsigned short*)(ws);                         // 1 MB
    float*          qT    = (float*)(ws + (1 << 20));                      // 1 MB
    unsigned short* PtHi  = (unsigned short*)(ws + (2 << 20));             // 64 KB
    unsigned short* PtLo  = (unsigned short*)(ws + (2 << 20) + (64 << 10));  // 64 KB
    float*          Pt32  = (float*)(ws + (2 << 20) + (128 << 10));        // 128 KB
    unsigned short* PdHi  = (unsigned short*)(ws + (2 << 20) + (256 << 10)); // 64 KB
    unsigned short* PdLo  = (unsigned short*)(ws + (2 << 20) + (320 << 10)); // 64 KB
    unsigned long long* wordsg = (unsigned long long*)(ws + (3 << 20));    // 8 MB
    float*          sning = (float*)(ws + (11 << 20));                     // 1 MB
    float*          su2g  = (float*)(ws + (12 << 20));                     // 8 MB
    unsigned long long* sidxpg = (unsigned long long*)(ws + (20 << 20));   // 2 MB

    qjl_prept<<<dim3(D_), dim3(S_), 0, stream>>>(proj, PtHi, PtLo, PdHi, PdLo, Pt32);
    qjl_sketch_q<<<dim3(B_ * HQ_), dim3(256), 0, stream>>>(query, proj, sqHi, qT);
    qjl_signs<<<dim3(N_ / TN, HK_, B_), dim3(256), 0, stream>>>(
        data, proj, oidx, PtHi, PtLo, PdHi, PdLo, Pt32, wordsg, sning, su2g, sidxpg);
    qjl_out<<<dim3(N_ / TN, HK_, B_), dim3(256), 0, stream>>>(
        sqHi, qT, wordsg, sning, su2g, sidxpg, out);
}

// Round 11
// 311.942 us; speedup vs baseline: 1.4498x; 1.0775x over previous
//
#include <hip/hip_runtime.h>
#include <hip/hip_bf16.h>
#include <math.h>

namespace {
constexpr int B_ = 4, HQ_ = 32, HK_ = 8, G_ = 4, M_ = 16;
constexpr int N_ = 8192, D_ = 128, S_ = 256, O_ = 8;
constexpr int TN = 64;               // n-rows per block
constexpr float TAU  = 1e-3f;        // inlier sign: |dot| below -> exact fp64 recheck
constexpr float TAUO = 1e-4f;        // outlier sign: |dot| below -> exact fp64 recheck
}

typedef short short8 __attribute__((ext_vector_type(8)));
typedef float f32x4 __attribute__((ext_vector_type(4)));
typedef unsigned int uint4_ __attribute__((ext_vector_type(4)));
typedef unsigned int uint2_ __attribute__((ext_vector_type(2)));
typedef unsigned long long ull2 __attribute__((ext_vector_type(2)));

__device__ inline unsigned short f2bf_rne(float f) {
    unsigned u = __float_as_uint(f);
    u += 0x7FFF + ((u >> 16) & 1);
    return (unsigned short)(u >> 16);
}
__device__ inline float bf2f(unsigned short h) {
    return __uint_as_float(((unsigned)h) << 16);
}

// ---------------- kernel P-split: PtHi/PtLo[s][d] = bf16 hi/lo of P[d][s]; Pt32 fp32 ----
__global__ __launch_bounds__(256) void qjl_prept(const float* __restrict__ P,
                                                 unsigned short* __restrict__ PtHi,
                                                 unsigned short* __restrict__ PtLo,
                                                 float* __restrict__ Pt32) {
    const int d = blockIdx.x;      // 0..127
    const int s = threadIdx.x;     // 0..255
    const float f = P[d * S_ + s];
    const unsigned short hb = f2bf_rne(f);
    const float lof = f - bf2f(hb);
    PtHi[s * D_ + d] = hb;
    PtLo[s * D_ + d] = f2bf_rne(lof);
    Pt32[s * D_ + d] = f;
}

// ---------------- kernel A: sqHi[head][m][s] = bf16(q · P); qT[head][d][m] = q^T ----
__global__ __launch_bounds__(256) void qjl_sketch_q(const float* __restrict__ q,
                                                    const float* __restrict__ P,
                                                    unsigned short* __restrict__ sqHi,
                                                    float* __restrict__ qT) {
    __shared__ float qs[M_][D_];
    const int tid = threadIdx.x;
    const size_t blk = blockIdx.x;  // b*HQ + hq
    const float* qb = q + blk * (size_t)(M_ * D_);
    for (int i = tid; i < M_ * D_ / 4; i += 256)
        reinterpret_cast<float4*>(&qs[0][0])[i] = reinterpret_cast<const float4*>(qb)[i];
    __syncthreads();
    float* qtb = qT + blk * (size_t)(D_ * M_);
    for (int i = tid; i < D_ * M_ / 4; i += 256) {
        const int d = i >> 2;
        const int m4 = i & 3;
        float4 v;
        v.x = qs[m4 * 4 + 0][d];
        v.y = qs[m4 * 4 + 1][d];
        v.z = qs[m4 * 4 + 2][d];
        v.w = qs[m4 * 4 + 3][d];
        reinterpret_cast<float4*>(qtb)[i] = v;
    }
    float acc[M_];
#pragma unroll
    for (int m = 0; m < M_; ++m) acc[m] = 0.f;
    const int s = tid;
    for (int d = 0; d < D_; ++d) {
        const float pv = P[d * S_ + s];
#pragma unroll
        for (int m = 0; m < M_; ++m) acc[m] = fmaf(qs[m][d], pv, acc[m]);
    }
    unsigned short* ob = sqHi + blk * (size_t)(M_ * S_);
#pragma unroll
    for (int m = 0; m < M_; ++m) ob[m * S_ + s] = f2bf_rne(acc[m]);
}

// rare cooperative path: exact fp64 sign of k_in[row] . P[:,col]; whole wave participates.
__device__ __noinline__ float qjl_fix_coop(const float* __restrict__ drow,
                                           const float* __restrict__ Pt32,
                                           int col, unsigned long long ip,
                                           float a, int src) {
    const int lane = threadIdx.x & 63;
    const float2 dv = *reinterpret_cast<const float2*>(&drow[2 * lane]);
    const float2 pv = *reinterpret_cast<const float2*>(&Pt32[(size_t)col * D_ + 2 * lane]);
    double p = 0.0;
#pragma unroll
    for (int e = 0; e < 2; ++e) {
        const int d = 2 * lane + e;
        const float v = e ? dv.y : dv.x;
        const float pw = e ? pv.y : pv.x;
        bool isout = false;
#pragma unroll
        for (int j = 0; j < 8; ++j)
            isout = isout || (((unsigned)(ip >> (8 * j)) & 0xFFu) == (unsigned)d);
        if (!isout) p = fma((double)v, (double)pw, p);
    }
#pragma unroll
    for (int off = 1; off < 64; off <<= 1) p += __shfl_xor(p, off);
    if (lane == src) a = (p > 0.0) ? 1.f : -1.f;
    return a;
}

// ---------------- kernel 1: signs + norms + outlier state ----------------
// R7 structure; phase B replaced by coalesced per-row column-parallel form (lane = t).
__global__ __launch_bounds__(256) void qjl_signs(const float* __restrict__ data,
                                                 const float* __restrict__ P,
                                                 const int* __restrict__ oidx,
                                                 const unsigned short* __restrict__ PtHi,
                                                 const unsigned short* __restrict__ PtLo,
                                                 const float* __restrict__ Pt32,
                                                 unsigned long long* __restrict__ wordsg,
                                                 float* __restrict__ sning,
                                                 float* __restrict__ su2g,
                                                 unsigned long long* __restrict__ sidxpg) {
    __shared__ unsigned short abuf[16384];        // 32 KB: hi [0..8191], lo [8192..], XOR-swz
    __shared__ unsigned long long sidxp[TN];
    __shared__ float svals[TN][O_];               // 2 KB: dedup'd outlier values (0 = dup)
    __shared__ float sfull[TN];
    __shared__ float snout[TN];

    const int tid = threadIdx.x;
    const int lane = tid & 63;
    const int wv = tid >> 6;
    const int l15 = lane & 15;
    const int kgrp = (lane >> 4) << 3;
    const int nt = blockIdx.x, hk = blockIdx.y, b = blockIdx.z;
    const int n0 = nt * TN;
    const size_t rowbase = (size_t)(b * HK_ + hk) * N_ + n0;
    const size_t wblk = (size_t)((b * HK_ + hk) * (N_ / TN) + nt);
    const float* dbase = data + ((size_t)(b * HK_ + hk) * N_) * D_;

    // ---- phase 0: load tile; truncation hi/lo split into abuf; per-row sumsq ----
    {
        const int r = tid >> 2;
        const int c = tid & 3;
        const float* drow = dbase + (size_t)(n0 + r) * D_;
        const int swz = (r & 7) << 3;
        float ssq = 0.f;
#pragma unroll
        for (int k = 0; k < 8; ++k) {
            const int f = c + 4 * k;
            float4 v = reinterpret_cast<const float4*>(drow)[f];
            ssq += v.x * v.x + v.y * v.y + v.z * v.z + v.w * v.w;
            const unsigned u0 = __float_as_uint(v.x), u1 = __float_as_uint(v.y);
            const unsigned u2 = __float_as_uint(v.z), u3 = __float_as_uint(v.w);
            const unsigned hw0 = (u0 >> 16) | (u1 & 0xFFFF0000u);
            const unsigned hw1 = (u2 >> 16) | (u3 & 0xFFFF0000u);
            const unsigned lu0 = __float_as_uint(v.x - __uint_as_float(u0 & 0xFFFF0000u));
            const unsigned lu1 = __float_as_uint(v.y - __uint_as_float(u1 & 0xFFFF0000u));
            const unsigned lu2 = __float_as_uint(v.z - __uint_as_float(u2 & 0xFFFF0000u));
            const unsigned lu3 = __float_as_uint(v.w - __uint_as_float(u3 & 0xFFFF0000u));
            const unsigned lw0 = (lu0 >> 16) | (lu1 & 0xFFFF0000u);
            const unsigned lw1 = (lu2 >> 16) | (lu3 & 0xFFFF0000u);
            const int ei = r * 128 + ((4 * f) ^ swz);
            *reinterpret_cast<uint2_*>(&abuf[ei]) = (uint2_){hw0, hw1};
            *reinterpret_cast<uint2_*>(&abuf[8192 + ei]) = (uint2_){lw0, lw1};
        }
        ssq += __shfl_xor(ssq, 1);
        ssq += __shfl_xor(ssq, 2);
        if (c == 0) sfull[r] = ssq;
    }
    __syncthreads();

    // ---- phase A: dedup outliers, zero them in LDS, record values, norms ----
    if (tid < TN) {
        const int n = tid;
        const int* ob = oidx + ((size_t)(b * HK_ + hk) * N_ + n0 + n) * O_;
        const float* drow = dbase + (size_t)(n0 + n) * D_;
        int id[O_];
        int4 i0 = reinterpret_cast<const int4*>(ob)[0];
        int4 i1 = reinterpret_cast<const int4*>(ob)[1];
        id[0] = i0.x; id[1] = i0.y; id[2] = i0.z; id[3] = i0.w;
        id[4] = i1.x; id[5] = i1.y; id[6] = i1.z; id[7] = i1.w;
        const int swz = (n & 7) << 3;
        unsigned long long ip = 0;
        float so2 = 0.f;
#pragma unroll
        for (int j = 0; j < O_; ++j) {
            bool dup = false;
#pragma unroll
            for (int jj = 0; jj < O_; ++jj)
                if (jj < j) dup = dup || (id[jj] == id[j]);
            if (!dup) {
                const float v = drow[id[j]];
                so2 = fmaf(v, v, so2);
                svals[n][j] = v;
                ip |= (unsigned long long)(id[j] & 0xFF) << (8 * j);
                const int ei = n * 128 + (id[j] ^ swz);
                abuf[ei] = 0;
                abuf[8192 + ei] = 0;
            } else {
                svals[n][j] = 0.f;
                ip |= 0xFFull << (8 * j);
            }
        }
        sidxp[n] = ip;
        sidxpg[rowbase + n] = ip;
        const float CIN = (float)(1.2533141373155003 / 256.0);
        const float COUT = (float)(1.2533141373155003 / 64.0);
        sning[rowbase + n] = CIN * sqrtf(fmaxf(sfull[n] - so2, 0.f));
        snout[n] = COUT * sqrtf(so2);
    }
    __syncthreads();

    // ---- phase B': sign_out + u, column-parallel (lane = t, SO==64); coalesced P reads ----
    {
        const int rbase = wv * 16;
#pragma unroll 2
        for (int r = 0; r < 16; ++r) {
            const int n = rbase + r;
            const unsigned long long ip = sidxp[n];
            float pv[O_], vv[O_];
#pragma unroll
            for (int j = 0; j < O_; ++j) {
                const unsigned bt = (unsigned)(ip >> (8 * j)) & 0xFFu;
                const int dd = (int)(bt & 0x7Fu);
                pv[j] = P[dd * S_ + lane];   // coalesced: one 256B row segment per j
                vv[j] = svals[n][j];         // 0 for dup slots -> no effect
            }
            float cs = 0.f;
#pragma unroll
            for (int j = 0; j < O_; ++j) cs = fmaf(vv[j], pv[j], cs);
            float sg;
            if (fabsf(cs) < TAUO) {          // rare per-lane exact path (same inputs, fp64)
                double cd = 0.0;
#pragma unroll
                for (int j = 0; j < O_; ++j) cd = fma((double)vv[j], (double)pv[j], cd);
                sg = (cd > 0.0) ? 1.f : ((cd < 0.0) ? -1.f : 0.f);
            } else {
                sg = (cs > 0.f) ? 1.f : -1.f;
            }
            float u[O_];
#pragma unroll
            for (int j = 0; j < O_; ++j) u[j] = sg * pv[j];
#pragma unroll
            for (int off = 1; off < 64; off <<= 1) {
#pragma unroll
                for (int j = 0; j < O_; ++j) u[j] += __shfl_xor(u[j], off);
            }
            if (lane == 0) {
                const float cno = snout[n];
                float o[O_];
#pragma unroll
                for (int j = 0; j < O_; ++j) {
                    const unsigned bt = (unsigned)(ip >> (8 * j)) & 0xFFu;
                    o[j] = (bt != 0xFFu) ? u[j] * cno : 0.f;
                }
                float* sp = su2g + (rowbase + n) * O_;
                *reinterpret_cast<f32x4*>(sp) = (f32x4){o[0], o[1], o[2], o[3]};
                *reinterpret_cast<f32x4*>(sp + 4) = (f32x4){o[4], o[5], o[6], o[7]};
            }
        }
    }
    // no barrier: phase C reads abuf (stable since phase A's barrier)

    // ---- phase C: signs via bf16 hi/lo MFMA; wave owns 64 cols (R7-measured config) ----
    {
        const int t0 = wv * 4;
#pragma unroll
        for (int ti = 0; ti < 4; ++ti) {
            const int t = t0 + ti;
            short8 bhi[4], blo[4];
            const size_t bo = (size_t)(16 * t + l15) * D_ + kgrp;
#pragma unroll
            for (int ks = 0; ks < 4; ++ks) {
                bhi[ks] = *reinterpret_cast<const short8*>(PtHi + bo + ks * 32);
                blo[ks] = *reinterpret_cast<const short8*>(PtLo + bo + ks * 32);
            }
#pragma unroll
            for (int rt = 0; rt < 4; ++rt) {
                const int arow = 16 * rt + l15;
                const int aswz = (arow & 7) << 3;
                short8 ahi[4], alo[4];
#pragma unroll
                for (int ks = 0; ks < 4; ++ks) {
                    const int ei = arow * 128 + ((ks * 32 + kgrp) ^ aswz);
                    ahi[ks] = *reinterpret_cast<const short8*>(&abuf[ei]);
                    alo[ks] = *reinterpret_cast<const short8*>(&abuf[8192 + ei]);
                }
                f32x4 ac1 = (f32x4){0.f, 0.f, 0.f, 0.f};
                f32x4 ac2 = (f32x4){0.f, 0.f, 0.f, 0.f};
                f32x4 ac3 = (f32x4){0.f, 0.f, 0.f, 0.f};
#pragma unroll
                for (int ks = 0; ks < 4; ++ks) {
                    ac1 = __builtin_amdgcn_mfma_f32_16x16x32_bf16(ahi[ks], bhi[ks], ac1, 0, 0, 0);
                    ac2 = __builtin_amdgcn_mfma_f32_16x16x32_bf16(ahi[ks], blo[ks], ac2, 0, 0, 0);
                    ac3 = __builtin_amdgcn_mfma_f32_16x16x32_bf16(alo[ks], bhi[ks], ac3, 0, 0, 0);
                }
                f32x4 a = (ac1 + ac2) + ac3;
                const float mn = fminf(fminf(fabsf(a[0]), fabsf(a[1])),
                                       fminf(fabsf(a[2]), fabsf(a[3])));
                if (__ballot(mn < TAU) != 0ull) {   // rare
#pragma unroll
                    for (int r = 0; r < 4; ++r) {
                        unsigned long long low = __ballot(fabsf(a[r]) < TAU);
                        while (low) {
                            const int src = __ffsll((unsigned long long)low) - 1;
                            low &= low - 1;
                            const int row = 16 * rt + ((src >> 4) << 2) + r;
                            const int col = 16 * t + (src & 15);
                            a[r] = qjl_fix_coop(dbase + (size_t)(n0 + row) * D_, Pt32, col,
                                                sidxp[row], a[r], src);
                        }
                    }
                }
                unsigned long long bb0 = __ballot(a[0] > 0.f);
                unsigned long long bb1 = __ballot(a[1] > 0.f);
                unsigned long long bb2 = __ballot(a[2] > 0.f);
                unsigned long long bb3 = __ballot(a[3] > 0.f);
                if (lane == 0) {
                    unsigned long long* wp = wordsg + (wblk * 256 + (size_t)(rt * 16 + t) * 4);
                    *reinterpret_cast<ull2*>(wp) = (ull2){bb0, bb1};
                    *reinterpret_cast<ull2*>(wp + 2) = (ull2){bb2, bb3};
                }
            }
        }
    }
}

// ---------------- kernel 2: expand signs + output GEMM (64-VGPR tier, no spills) ----
__global__ __launch_bounds__(256, 4) void qjl_out(const unsigned short* __restrict__ sqHi,
                                                  const float* __restrict__ qT,
                                                  const unsigned long long* __restrict__ wordsg,
                                                  const float* __restrict__ sning,
                                                  const float* __restrict__ su2g,
                                                  const unsigned long long* __restrict__ sidxpg,
                                                  float* __restrict__ out) {
    __shared__ unsigned short scol[16384];       // 32 KB: [n][256] bf16 = +/- cni, XOR-swz

    const int tid = threadIdx.x;
    const int lane = tid & 63;
    const int wv = tid >> 6;
    const int l15 = lane & 15;
    const int kgrp = (lane >> 4) << 3;
    const int nt = blockIdx.x, hk = blockIdx.y, b = blockIdx.z;
    const int n0 = nt * TN;
    const size_t rowbase = (size_t)(b * HK_ + hk) * N_ + n0;
    const size_t wblk = (size_t)((b * HK_ + hk) * (N_ / TN) + nt);
    const int hq = hk * G_ + wv;

    const unsigned short* sqb = sqHi + (size_t)(b * HQ_ + hq) * (M_ * S_);
    short8 aq[8];
#pragma unroll
    for (int ks = 0; ks < 8; ++ks)
        aq[ks] = *reinterpret_cast<const short8*>(sqb + (size_t)l15 * S_ + ks * 32 + kgrp);

    {
        const int n = tid & 63;
        const int c64 = tid >> 6;
        const unsigned short cb = f2bf_rne(sning[rowbase + n]);
        const unsigned base = (unsigned)cb | ((unsigned)cb << 16);
        const int g = (n >> 2) & 3;
        const int r = n & 3;
        const int w = n >> 4;
        const int swz = (n & 7) << 3;
        const unsigned long long* wbp = wordsg + wblk * 256;
#pragma unroll
        for (int i = 0; i < 4; ++i) {
            const int t = c64 * 4 + i;
            const unsigned long long wd = wbp[(size_t)(w * 16 + t) * 4 + r];
            const unsigned bits = (unsigned)(wd >> (16 * g)) & 0xFFFFu;
            const unsigned nb = ~bits;
            unsigned o[8];
#pragma unroll
            for (int p = 0; p < 8; ++p) {
                const unsigned m = (((nb >> (2 * p)) & 1u) << 15) |
                                   (((nb >> (2 * p + 1)) & 1u) << 31);
                o[p] = base ^ m;
            }
            const int s0 = c64 * 64 + i * 16;
            const int e0 = n * 256 + (s0 ^ swz);
            const int e1 = n * 256 + ((s0 + 8) ^ swz);
            *reinterpret_cast<uint4_*>(&scol[e0]) = (uint4_){o[0], o[1], o[2], o[3]};
            *reinterpret_cast<uint4_*>(&scol[e1]) = (uint4_){o[4], o[5], o[6], o[7]};
        }
    }
    __syncthreads();

    {
        const float* qtb = qT + (size_t)(b * HQ_ + hq) * (D_ * M_);
        const int m0 = (lane >> 4) << 2;
#pragma unroll
        for (int ct = 0; ct < 4; ++ct) {
            const int n = 16 * ct + l15;
            const size_t row = rowbase + n;
            const unsigned long long ip = sidxpg[row];
            const f32x4 s01 = *reinterpret_cast<const f32x4*>(su2g + row * O_);
            const f32x4 s23 = *reinterpret_cast<const f32x4*>(su2g + row * O_ + 4);
            const int nswz = (n & 7) << 3;
            f32x4 acc = (f32x4){0.f, 0.f, 0.f, 0.f};
#pragma unroll
            for (int ks = 0; ks < 8; ++ks) {
                const int ei = n * 256 + ((ks * 32 + kgrp) ^ nswz);
                const short8 bs = *reinterpret_cast<const short8*>(&scol[ei]);
                acc = __builtin_amdgcn_mfma_f32_16x16x32_bf16(aq[ks], bs, acc, 0, 0, 0);
            }
            float a0 = 0.f, a1 = 0.f, a2 = 0.f, a3 = 0.f;
#pragma unroll
            for (int j = 0; j < O_; ++j) {
                const float uj = (j < 4) ? s01[j & 3] : s23[j & 3];
                const int ix = (int)((ip >> (8 * j)) & 0x7Fu);
                const float4 qv = *reinterpret_cast<const float4*>(qtb + ix * M_ + m0);
                a0 = fmaf(uj, qv.x, a0);
                a1 = fmaf(uj, qv.y, a1);
                a2 = fmaf(uj, qv.z, a2);
                a3 = fmaf(uj, qv.w, a3);
            }
            acc[0] += a0; acc[1] += a1; acc[2] += a2; acc[3] += a3;
            float* ob = out + ((size_t)(b * HQ_ + hq) * N_ + (n0 + n)) * M_ + m0;
            *reinterpret_cast<f32x4*>(ob) = acc;
        }
    }
}

extern "C" void kernel_launch(void* const* d_in, const int* in_sizes, int n_in,
                              void* d_out, int out_size, void* d_ws, size_t ws_size,
                              hipStream_t stream) {
    const float* query = (const float*)d_in[0];  // [B][HQ][M][D]
    const float* data  = (const float*)d_in[1];  // [B][HK][N][D]
    const float* proj  = (const float*)d_in[2];  // [D][S]
    const int*   oidx  = (const int*)d_in[3];    // [B][HK][N][O]

    float* out = (float*)d_out;                  // [B][HQ][N][M]

    char* ws = (char*)d_ws;
    unsigned short* sqHi  = (unsigned short*)(ws);                     // 1 MB
    float*          qT    = (float*)(ws + (1 << 20));                  // 1 MB
    unsigned short* PtHi  = (unsigned short*)(ws + (2 << 20));         // 64 KB
    unsigned short* PtLo  = (unsigned short*)(ws + (2 << 20) + (64 << 10));   // 64 KB
    float*          Pt32  = (float*)(ws + (2 << 20) + (128 << 10));    // 128 KB
    unsigned long long* wordsg = (unsigned long long*)(ws + (3 << 20)); // 8 MB
    float*          sning = (float*)(ws + (11 << 20));                 // 1 MB
    float*          su2g  = (float*)(ws + (12 << 20));                 // 8 MB
    unsigned long long* sidxpg = (unsigned long long*)(ws + (20 << 20)); // 2 MB

    qjl_prept<<<dim3(D_), dim3(S_), 0, stream>>>(proj, PtHi, PtLo, Pt32);
    qjl_sketch_q<<<dim3(B_ * HQ_), dim3(256), 0, stream>>>(query, proj, sqHi, qT);
    qjl_signs<<<dim3(N_ / TN, HK_, B_), dim3(256), 0, stream>>>(
        data, proj, oidx, PtHi, PtLo, Pt32, wordsg, sning, su2g, sidxpg);
    qjl_out<<<dim3(N_ / TN, HK_, B_), dim3(256), 0, stream>>>(
        sqHi, qT, wordsg, sning, su2g, sidxpg, out);
}

// Round 12
// 223.920 us; speedup vs baseline: 2.0197x; 1.3931x over previous
//
#include <hip/hip_runtime.h>
#include <hip/hip_bf16.h>
#include <math.h>

namespace {
constexpr int B_ = 4, HQ_ = 32, HK_ = 8, G_ = 4, M_ = 16;
constexpr int N_ = 8192, D_ = 128, S_ = 256, O_ = 8;
constexpr int TN = 64;               // n-rows per block
constexpr float TAU  = 1e-3f;        // inlier sign: |dot| below -> exact fp64 recheck
constexpr float TAUO = 1e-4f;        // outlier sign: |dot| below -> exact fp64 recheck
constexpr int MAXSUS = 32;           // suspect-list capacity per wave (lambda ~0.07)
}

typedef short short8 __attribute__((ext_vector_type(8)));
typedef float f32x4 __attribute__((ext_vector_type(4)));
typedef unsigned int uint4_ __attribute__((ext_vector_type(4)));
typedef unsigned int uint2_ __attribute__((ext_vector_type(2)));

__device__ inline unsigned short f2bf_rne(float f) {
    unsigned u = __float_as_uint(f);
    u += 0x7FFF + ((u >> 16) & 1);
    return (unsigned short)(u >> 16);
}
__device__ inline float bf2f(unsigned short h) {
    return __uint_as_float(((unsigned)h) << 16);
}

// ---------------- kernel P-split: PtHi/PtLo[s][d] = bf16 hi/lo of P[d][s]; Pt32 fp32 ----
__global__ __launch_bounds__(256) void qjl_prept(const float* __restrict__ P,
                                                 unsigned short* __restrict__ PtHi,
                                                 unsigned short* __restrict__ PtLo,
                                                 float* __restrict__ Pt32) {
    const int d = blockIdx.x;      // 0..127
    const int s = threadIdx.x;     // 0..255
    const float f = P[d * S_ + s];
    const unsigned short hb = f2bf_rne(f);
    const float lof = f - bf2f(hb);
    PtHi[s * D_ + d] = hb;
    PtLo[s * D_ + d] = f2bf_rne(lof);
    Pt32[s * D_ + d] = f;
}

// ---------------- kernel A: sqHi[head][m][s] = bf16(q · P); qT[head][d][m] = q^T ----
__global__ __launch_bounds__(256) void qjl_sketch_q(const float* __restrict__ q,
                                                    const float* __restrict__ P,
                                                    unsigned short* __restrict__ sqHi,
                                                    float* __restrict__ qT) {
    __shared__ float qs[M_][D_];
    const int tid = threadIdx.x;
    const size_t blk = blockIdx.x;  // b*HQ + hq
    const float* qb = q + blk * (size_t)(M_ * D_);
    for (int i = tid; i < M_ * D_ / 4; i += 256)
        reinterpret_cast<float4*>(&qs[0][0])[i] = reinterpret_cast<const float4*>(qb)[i];
    __syncthreads();
    float* qtb = qT + blk * (size_t)(D_ * M_);
    for (int i = tid; i < D_ * M_ / 4; i += 256) {
        const int d = i >> 2;
        const int m4 = i & 3;
        float4 v;
        v.x = qs[m4 * 4 + 0][d];
        v.y = qs[m4 * 4 + 1][d];
        v.z = qs[m4 * 4 + 2][d];
        v.w = qs[m4 * 4 + 3][d];
        reinterpret_cast<float4*>(qtb)[i] = v;
    }
    float acc[M_];
#pragma unroll
    for (int m = 0; m < M_; ++m) acc[m] = 0.f;
    const int s = tid;
    for (int d = 0; d < D_; ++d) {
        const float pv = P[d * S_ + s];
#pragma unroll
        for (int m = 0; m < M_; ++m) acc[m] = fmaf(qs[m][d], pv, acc[m]);
    }
    unsigned short* ob = sqHi + blk * (size_t)(M_ * S_);
#pragma unroll
    for (int m = 0; m < M_; ++m) ob[m * S_ + s] = f2bf_rne(acc[m]);
}

// ---------------- kernel 1: signs + norms + outlier state (R7 structure) ----------------
// Deferred-fixup variant: ballot words staged in LDS; rare suspects resolved after the
// MFMA loop by inlined wave-cooperative fp64 dots (no function call -> zero scratch).
__global__ __launch_bounds__(256) void qjl_signs(const float* __restrict__ data,
                                                 const float* __restrict__ P,
                                                 const int* __restrict__ oidx,
                                                 const unsigned short* __restrict__ PtHi,
                                                 const unsigned short* __restrict__ PtLo,
                                                 const float* __restrict__ Pt32,
                                                 unsigned long long* __restrict__ wordsg,
                                                 float* __restrict__ sning,
                                                 float* __restrict__ su2g,
                                                 unsigned long long* __restrict__ sidxpg) {
    __shared__ unsigned short abuf[16384];        // 32 KB: hi [0..8191], lo [8192..], XOR-swz
    __shared__ unsigned long long lwords[256];    // 2 KB: ballot words [(rt*16+t)*4+r]
    __shared__ unsigned suslist[4][MAXSUS];       // 512 B: per-wave suspects (widx<<8|src)
    __shared__ unsigned long long sidxp[TN];
    __shared__ float svals[TN][O_];               // 2 KB: dedup'd outlier values (0 = dup)
    __shared__ float sfull[TN];
    __shared__ float snout[TN];

    const int tid = threadIdx.x;
    const int lane = tid & 63;
    const int wv = tid >> 6;
    const int l15 = lane & 15;
    const int kgrp = (lane >> 4) << 3;
    const int nt = blockIdx.x, hk = blockIdx.y, b = blockIdx.z;
    const int n0 = nt * TN;
    const size_t rowbase = (size_t)(b * HK_ + hk) * N_ + n0;
    const size_t wblk = (size_t)((b * HK_ + hk) * (N_ / TN) + nt);
    const float* dbase = data + ((size_t)(b * HK_ + hk) * N_) * D_;

    // ---- phase 0: load tile; truncation hi/lo split into abuf; per-row sumsq ----
    {
        const int r = tid >> 2;
        const int c = tid & 3;
        const float* drow = dbase + (size_t)(n0 + r) * D_;
        const int swz = (r & 7) << 3;
        float ssq = 0.f;
#pragma unroll
        for (int k = 0; k < 8; ++k) {
            const int f = c + 4 * k;
            float4 v = reinterpret_cast<const float4*>(drow)[f];
            ssq += v.x * v.x + v.y * v.y + v.z * v.z + v.w * v.w;
            const unsigned u0 = __float_as_uint(v.x), u1 = __float_as_uint(v.y);
            const unsigned u2 = __float_as_uint(v.z), u3 = __float_as_uint(v.w);
            const unsigned hw0 = (u0 >> 16) | (u1 & 0xFFFF0000u);
            const unsigned hw1 = (u2 >> 16) | (u3 & 0xFFFF0000u);
            const unsigned lu0 = __float_as_uint(v.x - __uint_as_float(u0 & 0xFFFF0000u));
            const unsigned lu1 = __float_as_uint(v.y - __uint_as_float(u1 & 0xFFFF0000u));
            const unsigned lu2 = __float_as_uint(v.z - __uint_as_float(u2 & 0xFFFF0000u));
            const unsigned lu3 = __float_as_uint(v.w - __uint_as_float(u3 & 0xFFFF0000u));
            const unsigned lw0 = (lu0 >> 16) | (lu1 & 0xFFFF0000u);
            const unsigned lw1 = (lu2 >> 16) | (lu3 & 0xFFFF0000u);
            const int ei = r * 128 + ((4 * f) ^ swz);
            *reinterpret_cast<uint2_*>(&abuf[ei]) = (uint2_){hw0, hw1};
            *reinterpret_cast<uint2_*>(&abuf[8192 + ei]) = (uint2_){lw0, lw1};
        }
        ssq += __shfl_xor(ssq, 1);
        ssq += __shfl_xor(ssq, 2);
        if (c == 0) sfull[r] = ssq;
    }
    __syncthreads();

    // ---- phase A: dedup outliers, zero them in LDS, record values, norms ----
    if (tid < TN) {
        const int n = tid;
        const int* ob = oidx + ((size_t)(b * HK_ + hk) * N_ + n0 + n) * O_;
        const float* drow = dbase + (size_t)(n0 + n) * D_;
        int id[O_];
        int4 i0 = reinterpret_cast<const int4*>(ob)[0];
        int4 i1 = reinterpret_cast<const int4*>(ob)[1];
        id[0] = i0.x; id[1] = i0.y; id[2] = i0.z; id[3] = i0.w;
        id[4] = i1.x; id[5] = i1.y; id[6] = i1.z; id[7] = i1.w;
        const int swz = (n & 7) << 3;
        unsigned long long ip = 0;
        float so2 = 0.f;
#pragma unroll
        for (int j = 0; j < O_; ++j) {
            bool dup = false;
#pragma unroll
            for (int jj = 0; jj < O_; ++jj)
                if (jj < j) dup = dup || (id[jj] == id[j]);
            if (!dup) {
                const float v = drow[id[j]];
                so2 = fmaf(v, v, so2);
                svals[n][j] = v;
                ip |= (unsigned long long)(id[j] & 0xFF) << (8 * j);
                const int ei = n * 128 + (id[j] ^ swz);
                abuf[ei] = 0;
                abuf[8192 + ei] = 0;
            } else {
                svals[n][j] = 0.f;
                ip |= 0xFFull << (8 * j);
            }
        }
        sidxp[n] = ip;
        sidxpg[rowbase + n] = ip;
        const float CIN = (float)(1.2533141373155003 / 256.0);
        const float COUT = (float)(1.2533141373155003 / 64.0);
        sning[rowbase + n] = CIN * sqrtf(fmaxf(sfull[n] - so2, 0.f));
        snout[n] = COUT * sqrtf(so2);
    }
    __syncthreads();

    // ---- phase B (R7 form): sign_out fp32 + rare fp64; 4 threads/row, float4 chunks ----
    {
        const int n = tid >> 2;
        const int c = tid & 3;
        const unsigned long long ip = sidxp[n];
        float u[O_], vv[O_];
        const float* pr[O_];
#pragma unroll
        for (int j = 0; j < O_; ++j) {
            u[j] = 0.f;
            const unsigned bt = (unsigned)(ip >> (8 * j)) & 0xFFu;
            const int ix = (int)(bt & 0x7Fu);
            pr[j] = P + ix * S_;
            vv[j] = svals[n][j];      // 0 for dup slots -> no effect
        }
#pragma unroll
        for (int ch = 0; ch < 4; ++ch) {
            const int tc = c * 16 + ch * 4;
            float4 pj[O_];
#pragma unroll
            for (int j = 0; j < O_; ++j)
                pj[j] = *reinterpret_cast<const float4*>(pr[j] + tc);
#pragma unroll
            for (int e = 0; e < 4; ++e) {
                float cs = 0.f;
#pragma unroll
                for (int j = 0; j < O_; ++j)
                    cs = fmaf(vv[j], pj[j][e], cs);
                float sg;
                if (fabsf(cs) < TAUO) {   // rare exact path
                    double cd = 0.0;
#pragma unroll
                    for (int j = 0; j < O_; ++j)
                        cd = fma((double)vv[j], (double)pj[j][e], cd);
                    sg = (cd > 0.0) ? 1.f : ((cd < 0.0) ? -1.f : 0.f);
                } else {
                    sg = (cs > 0.f) ? 1.f : -1.f;
                }
#pragma unroll
                for (int j = 0; j < O_; ++j)
                    u[j] = fmaf(sg, pj[j][e], u[j]);
            }
        }
#pragma unroll
        for (int j = 0; j < O_; ++j) {
            u[j] += __shfl_xor(u[j], 1);
            u[j] += __shfl_xor(u[j], 2);
        }
        if (c == 0) {
            const float cno = snout[n];
            float o[O_];
#pragma unroll
            for (int j = 0; j < O_; ++j) {
                const unsigned bt = (unsigned)(ip >> (8 * j)) & 0xFFu;
                o[j] = (bt != 0xFFu) ? u[j] * cno : 0.f;
            }
            float* sp = su2g + (rowbase + n) * O_;
            *reinterpret_cast<f32x4*>(sp) = (f32x4){o[0], o[1], o[2], o[3]};
            *reinterpret_cast<f32x4*>(sp + 4) = (f32x4){o[4], o[5], o[6], o[7]};
        }
    }
    // no barrier: phase C reads abuf (stable since phase A's barrier)

    // ---- phase C: signs via bf16 hi/lo MFMA -> LDS words; suspects deferred ----
    {
        int nsus = 0;                // wave-uniform (derived from ballots)
        const int t0 = wv * 4;
#pragma unroll
        for (int ti = 0; ti < 4; ++ti) {
            const int t = t0 + ti;
            short8 bhi[4], blo[4];
            const size_t bo = (size_t)(16 * t + l15) * D_ + kgrp;
#pragma unroll
            for (int ks = 0; ks < 4; ++ks) {
                bhi[ks] = *reinterpret_cast<const short8*>(PtHi + bo + ks * 32);
                blo[ks] = *reinterpret_cast<const short8*>(PtLo + bo + ks * 32);
            }
#pragma unroll
            for (int rt = 0; rt < 4; ++rt) {
                const int arow = 16 * rt + l15;
                const int aswz = (arow & 7) << 3;
                short8 ahi[4], alo[4];
#pragma unroll
                for (int ks = 0; ks < 4; ++ks) {
                    const int ei = arow * 128 + ((ks * 32 + kgrp) ^ aswz);
                    ahi[ks] = *reinterpret_cast<const short8*>(&abuf[ei]);
                    alo[ks] = *reinterpret_cast<const short8*>(&abuf[8192 + ei]);
                }
                f32x4 ac1 = (f32x4){0.f, 0.f, 0.f, 0.f};
                f32x4 ac2 = (f32x4){0.f, 0.f, 0.f, 0.f};
                f32x4 ac3 = (f32x4){0.f, 0.f, 0.f, 0.f};
#pragma unroll
                for (int ks = 0; ks < 4; ++ks) {
                    ac1 = __builtin_amdgcn_mfma_f32_16x16x32_bf16(ahi[ks], bhi[ks], ac1, 0, 0, 0);
                    ac2 = __builtin_amdgcn_mfma_f32_16x16x32_bf16(ahi[ks], blo[ks], ac2, 0, 0, 0);
                    ac3 = __builtin_amdgcn_mfma_f32_16x16x32_bf16(alo[ks], bhi[ks], ac3, 0, 0, 0);
                }
                f32x4 a = (ac1 + ac2) + ac3;
#pragma unroll
                for (int r = 0; r < 4; ++r) {
                    const int widx = (rt * 16 + t) * 4 + r;
                    const unsigned long long bb = __ballot(a[r] > 0.f);
                    if (lane == 0) lwords[widx] = bb;
                    unsigned long long low = __ballot(fabsf(a[r]) < TAU);
                    while (low) {                       // rare; wave-uniform loop
                        const int src = __ffsll((unsigned long long)low) - 1;
                        low &= low - 1;
                        if (nsus < MAXSUS) {
                            if (lane == 0)
                                suslist[wv][nsus] = ((unsigned)widx << 8) | (unsigned)src;
                            ++nsus;
                        }
                    }
                }
            }
        }

        // deferred suspects: inlined wave-cooperative exact fp64 dot, patch LDS word
        for (int i = 0; i < nsus; ++i) {
            const unsigned e = suslist[wv][i];
            const int widx = (int)(e >> 8), src = (int)(e & 63u);
            const int t = (widx >> 2) & 15, rt = widx >> 6, r = widx & 3;
            const int row = 16 * rt + ((src >> 4) << 2) + r;
            const int col = 16 * t + (src & 15);
            const float* drow = dbase + (size_t)(n0 + row) * D_;
            const unsigned long long ip = sidxp[row];
            const float2 dv = *reinterpret_cast<const float2*>(&drow[2 * lane]);
            const float2 pv = *reinterpret_cast<const float2*>(&Pt32[(size_t)col * D_ + 2 * lane]);
            double p = 0.0;
#pragma unroll
            for (int ee = 0; ee < 2; ++ee) {
                const int d = 2 * lane + ee;
                const float v = ee ? dv.y : dv.x;
                const float pw = ee ? pv.y : pv.x;
                bool isout = false;
#pragma unroll
                for (int j = 0; j < 8; ++j)
                    isout = isout || (((unsigned)(ip >> (8 * j)) & 0xFFu) == (unsigned)d);
                if (!isout) p = fma((double)v, (double)pw, p);
            }
#pragma unroll
            for (int off = 1; off < 64; off <<= 1) p += __shfl_xor(p, off);
            if (lane == 0) {
                const unsigned long long bit = 1ull << src;
                const unsigned long long w = lwords[widx];
                lwords[widx] = (p > 0.0) ? (w | bit) : (w & ~bit);
            }
        }

        // coalesced word store: each lane writes one of the wave's 64 words
        const int idx = (lane >> 4) * 64 + wv * 16 + (lane & 15);
        wordsg[wblk * 256 + idx] = lwords[idx];
    }
}

// ---------------- kernel 2: expand signs + output GEMM (64-VGPR tier, no spills) ----
__global__ __launch_bounds__(256, 4) void qjl_out(const unsigned short* __restrict__ sqHi,
                                                  const float* __restrict__ qT,
                                                  const unsigned long long* __restrict__ wordsg,
                                                  const float* __restrict__ sning,
                                                  const float* __restrict__ su2g,
                                                  const unsigned long long* __restrict__ sidxpg,
                                                  float* __restrict__ out) {
    __shared__ unsigned short scol[16384];       // 32 KB: [n][256] bf16 = +/- cni, XOR-swz

    const int tid = threadIdx.x;
    const int lane = tid & 63;
    const int wv = tid >> 6;
    const int l15 = lane & 15;
    const int kgrp = (lane >> 4) << 3;
    const int nt = blockIdx.x, hk = blockIdx.y, b = blockIdx.z;
    const int n0 = nt * TN;
    const size_t rowbase = (size_t)(b * HK_ + hk) * N_ + n0;
    const size_t wblk = (size_t)((b * HK_ + hk) * (N_ / TN) + nt);
    const int hq = hk * G_ + wv;

    const unsigned short* sqb = sqHi + (size_t)(b * HQ_ + hq) * (M_ * S_);
    short8 aq[8];
#pragma unroll
    for (int ks = 0; ks < 8; ++ks)
        aq[ks] = *reinterpret_cast<const short8*>(sqb + (size_t)l15 * S_ + ks * 32 + kgrp);

    {
        const int n = tid & 63;
        const int c64 = tid >> 6;
        const unsigned short cb = f2bf_rne(sning[rowbase + n]);
        const unsigned base = (unsigned)cb | ((unsigned)cb << 16);
        const int g = (n >> 2) & 3;
        const int r = n & 3;
        const int w = n >> 4;
        const int swz = (n & 7) << 3;
        const unsigned long long* wbp = wordsg + wblk * 256;
#pragma unroll
        for (int i = 0; i < 4; ++i) {
            const int t = c64 * 4 + i;
            const unsigned long long wd = wbp[(size_t)(w * 16 + t) * 4 + r];
            const unsigned bits = (unsigned)(wd >> (16 * g)) & 0xFFFFu;
            const unsigned nb = ~bits;
            unsigned o[8];
#pragma unroll
            for (int p = 0; p < 8; ++p) {
                const unsigned m = (((nb >> (2 * p)) & 1u) << 15) |
                                   (((nb >> (2 * p + 1)) & 1u) << 31);
                o[p] = base ^ m;
            }
            const int s0 = c64 * 64 + i * 16;
            const int e0 = n * 256 + (s0 ^ swz);
            const int e1 = n * 256 + ((s0 + 8) ^ swz);
            *reinterpret_cast<uint4_*>(&scol[e0]) = (uint4_){o[0], o[1], o[2], o[3]};
            *reinterpret_cast<uint4_*>(&scol[e1]) = (uint4_){o[4], o[5], o[6], o[7]};
        }
    }
    __syncthreads();

    {
        const float* qtb = qT + (size_t)(b * HQ_ + hq) * (D_ * M_);
        const int m0 = (lane >> 4) << 2;
#pragma unroll
        for (int ct = 0; ct < 4; ++ct) {
            const int n = 16 * ct + l15;
            const size_t row = rowbase + n;
            const unsigned long long ip = sidxpg[row];
            const f32x4 s01 = *reinterpret_cast<const f32x4*>(su2g + row * O_);
            const f32x4 s23 = *reinterpret_cast<const f32x4*>(su2g + row * O_ + 4);
            const int nswz = (n & 7) << 3;
            f32x4 acc = (f32x4){0.f, 0.f, 0.f, 0.f};
#pragma unroll
            for (int ks = 0; ks < 8; ++ks) {
                const int ei = n * 256 + ((ks * 32 + kgrp) ^ nswz);
                const short8 bs = *reinterpret_cast<const short8*>(&scol[ei]);
                acc = __builtin_amdgcn_mfma_f32_16x16x32_bf16(aq[ks], bs, acc, 0, 0, 0);
            }
            float a0 = 0.f, a1 = 0.f, a2 = 0.f, a3 = 0.f;
#pragma unroll
            for (int j = 0; j < O_; ++j) {
                const float uj = (j < 4) ? s01[j & 3] : s23[j & 3];
                const int ix = (int)((ip >> (8 * j)) & 0x7Fu);
                const float4 qv = *reinterpret_cast<const float4*>(qtb + ix * M_ + m0);
                a0 = fmaf(uj, qv.x, a0);
                a1 = fmaf(uj, qv.y, a1);
                a2 = fmaf(uj, qv.z, a2);
                a3 = fmaf(uj, qv.w, a3);
            }
            acc[0] += a0; acc[1] += a1; acc[2] += a2; acc[3] += a3;
            float* ob = out + ((size_t)(b * HQ_ + hq) * N_ + (n0 + n)) * M_ + m0;
            *reinterpret_cast<f32x4*>(ob) = acc;
        }
    }
}

extern "C" void kernel_launch(void* const* d_in, const int* in_sizes, int n_in,
                              void* d_out, int out_size, void* d_ws, size_t ws_size,
                              hipStream_t stream) {
    const float* query = (const float*)d_in[0];  // [B][HQ][M][D]
    const float* data  = (const float*)d_in[1];  // [B][HK][N][D]
    const float* proj  = (const float*)d_in[2];  // [D][S]
    const int*   oidx  = (const int*)d_in[3];    // [B][HK][N][O]

    float* out = (float*)d_out;                  // [B][HQ][N][M]

    char* ws = (char*)d_ws;
    unsigned short* sqHi  = (unsigned short*)(ws);                     // 1 MB
    float*          qT    = (float*)(ws + (1 << 20));                  // 1 MB
    unsigned short* PtHi  = (unsigned short*)(ws + (2 << 20));         // 64 KB
    unsigned short* PtLo  = (unsigned short*)(ws + (2 << 20) + (64 << 10));   // 64 KB
    float*          Pt32  = (float*)(ws + (2 << 20) + (128 << 10));    // 128 KB
    unsigned long long* wordsg = (unsigned long long*)(ws + (3 << 20)); // 8 MB
    float*          sning = (float*)(ws + (11 << 20));                 // 1 MB
    float*          su2g  = (float*)(ws + (12 << 20));                 // 8 MB
    unsigned long long* sidxpg = (unsigned long long*)(ws + (20 << 20)); // 2 MB

    qjl_prept<<<dim3(D_), dim3(S_), 0, stream>>>(proj, PtHi, PtLo, Pt32);
    qjl_sketch_q<<<dim3(B_ * HQ_), dim3(256), 0, stream>>>(query, proj, sqHi, qT);
    qjl_signs<<<dim3(N_ / TN, HK_, B_), dim3(256), 0, stream>>>(
        data, proj, oidx, PtHi, PtLo, Pt32, wordsg, sning, su2g, sidxpg);
    qjl_out<<<dim3(N_ / TN, HK_, B_), dim3(256), 0, stream>>>(
        sqHi, qT, wordsg, sning, su2g, sidxpg, out);
}

// Round 13
// 218.726 us; speedup vs baseline: 2.0677x; 1.0237x over previous
//
#include <hip/hip_runtime.h>
#include <hip/hip_bf16.h>
#include <math.h>

namespace {
constexpr int B_ = 4, HQ_ = 32, HK_ = 8, G_ = 4, M_ = 16;
constexpr int N_ = 8192, D_ = 128, S_ = 256, O_ = 8;
constexpr int TN = 64;               // n-rows per block
constexpr float TAU  = 1e-3f;        // inlier sign: |dot| below -> exact fp64 recheck
constexpr float TAUO = 1e-4f;        // outlier sign: |dot| below -> exact fp64 recheck
constexpr int MAXSUS = 32;           // suspect-list capacity per wave
}

typedef short short8 __attribute__((ext_vector_type(8)));
typedef float f32x4 __attribute__((ext_vector_type(4)));
typedef unsigned int uint4_ __attribute__((ext_vector_type(4)));
typedef unsigned int uint2_ __attribute__((ext_vector_type(2)));

__device__ inline unsigned short f2bf_rne(float f) {
    unsigned u = __float_as_uint(f);
    u += 0x7FFF + ((u >> 16) & 1);
    return (unsigned short)(u >> 16);
}
__device__ inline float bf2f(unsigned short h) {
    return __uint_as_float(((unsigned)h) << 16);
}

// ---------------- kernel P-split: PtHi/PtLo[s][d] = bf16 hi/lo of P[d][s]; Pt32 fp32 ----
__global__ __launch_bounds__(256) void qjl_prept(const float* __restrict__ P,
                                                 unsigned short* __restrict__ PtHi,
                                                 unsigned short* __restrict__ PtLo,
                                                 float* __restrict__ Pt32) {
    const int d = blockIdx.x;      // 0..127
    const int s = threadIdx.x;     // 0..255
    const float f = P[d * S_ + s];
    const unsigned short hb = f2bf_rne(f);
    const float lof = f - bf2f(hb);
    PtHi[s * D_ + d] = hb;
    PtLo[s * D_ + d] = f2bf_rne(lof);
    Pt32[s * D_ + d] = f;
}

// ---------------- kernel A: sqHi[head][m][s] = bf16(q · P); qT[head][d][m] = q^T ----
__global__ __launch_bounds__(256) void qjl_sketch_q(const float* __restrict__ q,
                                                    const float* __restrict__ P,
                                                    unsigned short* __restrict__ sqHi,
                                                    float* __restrict__ qT) {
    __shared__ float qs[M_][D_];
    const int tid = threadIdx.x;
    const size_t blk = blockIdx.x;  // b*HQ + hq
    const float* qb = q + blk * (size_t)(M_ * D_);
    for (int i = tid; i < M_ * D_ / 4; i += 256)
        reinterpret_cast<float4*>(&qs[0][0])[i] = reinterpret_cast<const float4*>(qb)[i];
    __syncthreads();
    float* qtb = qT + blk * (size_t)(D_ * M_);
    for (int i = tid; i < D_ * M_ / 4; i += 256) {
        const int d = i >> 2;
        const int m4 = i & 3;
        float4 v;
        v.x = qs[m4 * 4 + 0][d];
        v.y = qs[m4 * 4 + 1][d];
        v.z = qs[m4 * 4 + 2][d];
        v.w = qs[m4 * 4 + 3][d];
        reinterpret_cast<float4*>(qtb)[i] = v;
    }
    float acc[M_];
#pragma unroll
    for (int m = 0; m < M_; ++m) acc[m] = 0.f;
    const int s = tid;
    for (int d = 0; d < D_; ++d) {
        const float pv = P[d * S_ + s];
#pragma unroll
        for (int m = 0; m < M_; ++m) acc[m] = fmaf(qs[m][d], pv, acc[m]);
    }
    unsigned short* ob = sqHi + blk * (size_t)(M_ * S_);
#pragma unroll
    for (int m = 0; m < M_; ++m) ob[m * S_ + s] = f2bf_rne(acc[m]);
}

// ---------------- kernel 1: signs + norms + outlier state ----------------
// R12 structure; phase C register-blocked: A fragments for all 4 row-tiles cached in
// VGPRs (we are pinned at the 2-waves/SIMD tier by unified VGPR+AGPR anyway, so the
// extra ~100 VGPR are free) -> LDS reads drop 128 -> 32 per wave.
__global__ __launch_bounds__(256) void qjl_signs(const float* __restrict__ data,
                                                 const float* __restrict__ P,
                                                 const int* __restrict__ oidx,
                                                 const unsigned short* __restrict__ PtHi,
                                                 const unsigned short* __restrict__ PtLo,
                                                 const float* __restrict__ Pt32,
                                                 unsigned long long* __restrict__ wordsg,
                                                 float* __restrict__ sning,
                                                 float* __restrict__ su2g,
                                                 unsigned long long* __restrict__ sidxpg) {
    __shared__ unsigned short abuf[16384];        // 32 KB: hi [0..8191], lo [8192..], XOR-swz
    __shared__ unsigned long long lwords[256];    // 2 KB: ballot words [(rt*16+t)*4+r]
    __shared__ unsigned suslist[4][MAXSUS];       // 512 B: per-wave suspects (widx<<8|src)
    __shared__ unsigned long long sidxp[TN];
    __shared__ float svals[TN][O_];               // 2 KB: dedup'd outlier values (0 = dup)
    __shared__ float sfull[TN];
    __shared__ float snout[TN];

    const int tid = threadIdx.x;
    const int lane = tid & 63;
    const int wv = tid >> 6;
    const int l15 = lane & 15;
    const int kgrp = (lane >> 4) << 3;
    const int nt = blockIdx.x, hk = blockIdx.y, b = blockIdx.z;
    const int n0 = nt * TN;
    const size_t rowbase = (size_t)(b * HK_ + hk) * N_ + n0;
    const size_t wblk = (size_t)((b * HK_ + hk) * (N_ / TN) + nt);
    const float* dbase = data + ((size_t)(b * HK_ + hk) * N_) * D_;

    // ---- phase 0: load tile; truncation hi/lo split into abuf; per-row sumsq ----
    {
        const int r = tid >> 2;
        const int c = tid & 3;
        const float* drow = dbase + (size_t)(n0 + r) * D_;
        const int swz = (r & 7) << 3;
        float ssq = 0.f;
#pragma unroll
        for (int k = 0; k < 8; ++k) {
            const int f = c + 4 * k;
            float4 v = reinterpret_cast<const float4*>(drow)[f];
            ssq += v.x * v.x + v.y * v.y + v.z * v.z + v.w * v.w;
            const unsigned u0 = __float_as_uint(v.x), u1 = __float_as_uint(v.y);
            const unsigned u2 = __float_as_uint(v.z), u3 = __float_as_uint(v.w);
            const unsigned hw0 = (u0 >> 16) | (u1 & 0xFFFF0000u);
            const unsigned hw1 = (u2 >> 16) | (u3 & 0xFFFF0000u);
            const unsigned lu0 = __float_as_uint(v.x - __uint_as_float(u0 & 0xFFFF0000u));
            const unsigned lu1 = __float_as_uint(v.y - __uint_as_float(u1 & 0xFFFF0000u));
            const unsigned lu2 = __float_as_uint(v.z - __uint_as_float(u2 & 0xFFFF0000u));
            const unsigned lu3 = __float_as_uint(v.w - __uint_as_float(u3 & 0xFFFF0000u));
            const unsigned lw0 = (lu0 >> 16) | (lu1 & 0xFFFF0000u);
            const unsigned lw1 = (lu2 >> 16) | (lu3 & 0xFFFF0000u);
            const int ei = r * 128 + ((4 * f) ^ swz);
            *reinterpret_cast<uint2_*>(&abuf[ei]) = (uint2_){hw0, hw1};
            *reinterpret_cast<uint2_*>(&abuf[8192 + ei]) = (uint2_){lw0, lw1};
        }
        ssq += __shfl_xor(ssq, 1);
        ssq += __shfl_xor(ssq, 2);
        if (c == 0) sfull[r] = ssq;
    }
    __syncthreads();

    // ---- phase A: dedup outliers, zero them in LDS, record values, norms ----
    if (tid < TN) {
        const int n = tid;
        const int* ob = oidx + ((size_t)(b * HK_ + hk) * N_ + n0 + n) * O_;
        const float* drow = dbase + (size_t)(n0 + n) * D_;
        int id[O_];
        int4 i0 = reinterpret_cast<const int4*>(ob)[0];
        int4 i1 = reinterpret_cast<const int4*>(ob)[1];
        id[0] = i0.x; id[1] = i0.y; id[2] = i0.z; id[3] = i0.w;
        id[4] = i1.x; id[5] = i1.y; id[6] = i1.z; id[7] = i1.w;
        const int swz = (n & 7) << 3;
        unsigned long long ip = 0;
        float so2 = 0.f;
#pragma unroll
        for (int j = 0; j < O_; ++j) {
            bool dup = false;
#pragma unroll
            for (int jj = 0; jj < O_; ++jj)
                if (jj < j) dup = dup || (id[jj] == id[j]);
            if (!dup) {
                const float v = drow[id[j]];
                so2 = fmaf(v, v, so2);
                svals[n][j] = v;
                ip |= (unsigned long long)(id[j] & 0xFF) << (8 * j);
                const int ei = n * 128 + (id[j] ^ swz);
                abuf[ei] = 0;
                abuf[8192 + ei] = 0;
            } else {
                svals[n][j] = 0.f;
                ip |= 0xFFull << (8 * j);
            }
        }
        sidxp[n] = ip;
        sidxpg[rowbase + n] = ip;
        const float CIN = (float)(1.2533141373155003 / 256.0);
        const float COUT = (float)(1.2533141373155003 / 64.0);
        sning[rowbase + n] = CIN * sqrtf(fmaxf(sfull[n] - so2, 0.f));
        snout[n] = COUT * sqrtf(so2);
    }
    __syncthreads();

    // ---- phase B (R7 form): sign_out fp32 + rare fp64; 4 threads/row, float4 chunks ----
    {
        const int n = tid >> 2;
        const int c = tid & 3;
        const unsigned long long ip = sidxp[n];
        float u[O_], vv[O_];
        const float* pr[O_];
#pragma unroll
        for (int j = 0; j < O_; ++j) {
            u[j] = 0.f;
            const unsigned bt = (unsigned)(ip >> (8 * j)) & 0xFFu;
            const int ix = (int)(bt & 0x7Fu);
            pr[j] = P + ix * S_;
            vv[j] = svals[n][j];      // 0 for dup slots -> no effect
        }
#pragma unroll
        for (int ch = 0; ch < 4; ++ch) {
            const int tc = c * 16 + ch * 4;
            float4 pj[O_];
#pragma unroll
            for (int j = 0; j < O_; ++j)
                pj[j] = *reinterpret_cast<const float4*>(pr[j] + tc);
#pragma unroll
            for (int e = 0; e < 4; ++e) {
                float cs = 0.f;
#pragma unroll
                for (int j = 0; j < O_; ++j)
                    cs = fmaf(vv[j], pj[j][e], cs);
                float sg;
                if (fabsf(cs) < TAUO) {   // rare exact path
                    double cd = 0.0;
#pragma unroll
                    for (int j = 0; j < O_; ++j)
                        cd = fma((double)vv[j], (double)pj[j][e], cd);
                    sg = (cd > 0.0) ? 1.f : ((cd < 0.0) ? -1.f : 0.f);
                } else {
                    sg = (cs > 0.f) ? 1.f : -1.f;
                }
#pragma unroll
                for (int j = 0; j < O_; ++j)
                    u[j] = fmaf(sg, pj[j][e], u[j]);
            }
        }
#pragma unroll
        for (int j = 0; j < O_; ++j) {
            u[j] += __shfl_xor(u[j], 1);
            u[j] += __shfl_xor(u[j], 2);
        }
        if (c == 0) {
            const float cno = snout[n];
            float o[O_];
#pragma unroll
            for (int j = 0; j < O_; ++j) {
                const unsigned bt = (unsigned)(ip >> (8 * j)) & 0xFFu;
                o[j] = (bt != 0xFFu) ? u[j] * cno : 0.f;
            }
            float* sp = su2g + (rowbase + n) * O_;
            *reinterpret_cast<f32x4*>(sp) = (f32x4){o[0], o[1], o[2], o[3]};
            *reinterpret_cast<f32x4*>(sp + 4) = (f32x4){o[4], o[5], o[6], o[7]};
        }
    }
    // no barrier: phase C reads abuf (stable since phase A's barrier)

    // ---- phase C: signs via bf16 hi/lo MFMA; A register-cached for all 4 row-tiles ----
    {
        int nsus = 0;                // wave-uniform (derived from ballots)
        const int t0 = wv * 4;

        // A fragments for ALL 4 row-tiles, loaded ONCE (32 ds_read_b128 -> 128 VGPR)
        short8 Ahi[4][4], Alo[4][4];           // [rt][ks], all indices compile-time
#pragma unroll
        for (int rt = 0; rt < 4; ++rt) {
            const int arow = 16 * rt + l15;
            const int aswz = (arow & 7) << 3;
#pragma unroll
            for (int ks = 0; ks < 4; ++ks) {
                const int ei = arow * 128 + ((ks * 32 + kgrp) ^ aswz);
                Ahi[rt][ks] = *reinterpret_cast<const short8*>(&abuf[ei]);
                Alo[rt][ks] = *reinterpret_cast<const short8*>(&abuf[8192 + ei]);
            }
        }

#pragma unroll
        for (int ti = 0; ti < 4; ++ti) {
            const int t = t0 + ti;
            short8 bhi[4], blo[4];
            const size_t bo = (size_t)(16 * t + l15) * D_ + kgrp;
#pragma unroll
            for (int ks = 0; ks < 4; ++ks) {
                bhi[ks] = *reinterpret_cast<const short8*>(PtHi + bo + ks * 32);
                blo[ks] = *reinterpret_cast<const short8*>(PtLo + bo + ks * 32);
            }
#pragma unroll
            for (int rt = 0; rt < 4; ++rt) {
                f32x4 ac1 = (f32x4){0.f, 0.f, 0.f, 0.f};
                f32x4 ac2 = (f32x4){0.f, 0.f, 0.f, 0.f};
                f32x4 ac3 = (f32x4){0.f, 0.f, 0.f, 0.f};
#pragma unroll
                for (int ks = 0; ks < 4; ++ks) {
                    ac1 = __builtin_amdgcn_mfma_f32_16x16x32_bf16(Ahi[rt][ks], bhi[ks], ac1, 0, 0, 0);
                    ac2 = __builtin_amdgcn_mfma_f32_16x16x32_bf16(Ahi[rt][ks], blo[ks], ac2, 0, 0, 0);
                    ac3 = __builtin_amdgcn_mfma_f32_16x16x32_bf16(Alo[rt][ks], bhi[ks], ac3, 0, 0, 0);
                }
                f32x4 a = (ac1 + ac2) + ac3;
#pragma unroll
                for (int r = 0; r < 4; ++r) {
                    const int widx = (rt * 16 + t) * 4 + r;
                    const unsigned long long bb = __ballot(a[r] > 0.f);
                    if (lane == 0) lwords[widx] = bb;
                    unsigned long long low = __ballot(fabsf(a[r]) < TAU);
                    while (low) {                       // rare; wave-uniform loop
                        const int src = __ffsll((unsigned long long)low) - 1;
                        low &= low - 1;
                        if (nsus < MAXSUS) {
                            if (lane == 0)
                                suslist[wv][nsus] = ((unsigned)widx << 8) | (unsigned)src;
                            ++nsus;
                        }
                    }
                }
            }
        }

        // deferred suspects: inlined wave-cooperative exact fp64 dot, patch LDS word
        for (int i = 0; i < nsus; ++i) {
            const unsigned e = suslist[wv][i];
            const int widx = (int)(e >> 8), src = (int)(e & 63u);
            const int t = (widx >> 2) & 15, rt = widx >> 6, r = widx & 3;
            const int row = 16 * rt + ((src >> 4) << 2) + r;
            const int col = 16 * t + (src & 15);
            const float* drow = dbase + (size_t)(n0 + row) * D_;
            const unsigned long long ip = sidxp[row];
            const float2 dv = *reinterpret_cast<const float2*>(&drow[2 * lane]);
            const float2 pv = *reinterpret_cast<const float2*>(&Pt32[(size_t)col * D_ + 2 * lane]);
            double p = 0.0;
#pragma unroll
            for (int ee = 0; ee < 2; ++ee) {
                const int d = 2 * lane + ee;
                const float v = ee ? dv.y : dv.x;
                const float pw = ee ? pv.y : pv.x;
                bool isout = false;
#pragma unroll
                for (int j = 0; j < 8; ++j)
                    isout = isout || (((unsigned)(ip >> (8 * j)) & 0xFFu) == (unsigned)d);
                if (!isout) p = fma((double)v, (double)pw, p);
            }
#pragma unroll
            for (int off = 1; off < 64; off <<= 1) p += __shfl_xor(p, off);
            if (lane == 0) {
                const unsigned long long bit = 1ull << src;
                const unsigned long long w = lwords[widx];
                lwords[widx] = (p > 0.0) ? (w | bit) : (w & ~bit);
            }
        }

        // coalesced word store: each lane writes one of the wave's 64 words
        const int idx = (lane >> 4) * 64 + wv * 16 + (lane & 15);
        wordsg[wblk * 256 + idx] = lwords[idx];
    }
}

// ---------------- kernel 2: expand signs + output GEMM (64-VGPR tier, no spills) ----
__global__ __launch_bounds__(256, 4) void qjl_out(const unsigned short* __restrict__ sqHi,
                                                  const float* __restrict__ qT,
                                                  const unsigned long long* __restrict__ wordsg,
                                                  const float* __restrict__ sning,
                                                  const float* __restrict__ su2g,
                                                  const unsigned long long* __restrict__ sidxpg,
                                                  float* __restrict__ out) {
    __shared__ unsigned short scol[16384];       // 32 KB: [n][256] bf16 = +/- cni, XOR-swz

    const int tid = threadIdx.x;
    const int lane = tid & 63;
    const int wv = tid >> 6;
    const int l15 = lane & 15;
    const int kgrp = (lane >> 4) << 3;
    const int nt = blockIdx.x, hk = blockIdx.y, b = blockIdx.z;
    const int n0 = nt * TN;
    const size_t rowbase = (size_t)(b * HK_ + hk) * N_ + n0;
    const size_t wblk = (size_t)((b * HK_ + hk) * (N_ / TN) + nt);
    const int hq = hk * G_ + wv;

    const unsigned short* sqb = sqHi + (size_t)(b * HQ_ + hq) * (M_ * S_);
    short8 aq[8];
#pragma unroll
    for (int ks = 0; ks < 8; ++ks)
        aq[ks] = *reinterpret_cast<const short8*>(sqb + (size_t)l15 * S_ + ks * 32 + kgrp);

    {
        const int n = tid & 63;
        const int c64 = tid >> 6;
        const unsigned short cb = f2bf_rne(sning[rowbase + n]);
        const unsigned base = (unsigned)cb | ((unsigned)cb << 16);
        const int g = (n >> 2) & 3;
        const int r = n & 3;
        const int w = n >> 4;
        const int swz = (n & 7) << 3;
        const unsigned long long* wbp = wordsg + wblk * 256;
#pragma unroll
        for (int i = 0; i < 4; ++i) {
            const int t = c64 * 4 + i;
            const unsigned long long wd = wbp[(size_t)(w * 16 + t) * 4 + r];
            const unsigned bits = (unsigned)(wd >> (16 * g)) & 0xFFFFu;
            const unsigned nb = ~bits;
            unsigned o[8];
#pragma unroll
            for (int p = 0; p < 8; ++p) {
                const unsigned m = (((nb >> (2 * p)) & 1u) << 15) |
                                   (((nb >> (2 * p + 1)) & 1u) << 31);
                o[p] = base ^ m;
            }
            const int s0 = c64 * 64 + i * 16;
            const int e0 = n * 256 + (s0 ^ swz);
            const int e1 = n * 256 + ((s0 + 8) ^ swz);
            *reinterpret_cast<uint4_*>(&scol[e0]) = (uint4_){o[0], o[1], o[2], o[3]};
            *reinterpret_cast<uint4_*>(&scol[e1]) = (uint4_){o[4], o[5], o[6], o[7]};
        }
    }
    __syncthreads();

    {
        const float* qtb = qT + (size_t)(b * HQ_ + hq) * (D_ * M_);
        const int m0 = (lane >> 4) << 2;
#pragma unroll
        for (int ct = 0; ct < 4; ++ct) {
            const int n = 16 * ct + l15;
            const size_t row = rowbase + n;
            const unsigned long long ip = sidxpg[row];
            const f32x4 s01 = *reinterpret_cast<const f32x4*>(su2g + row * O_);
            const f32x4 s23 = *reinterpret_cast<const f32x4*>(su2g + row * O_ + 4);
            const int nswz = (n & 7) << 3;
            f32x4 acc = (f32x4){0.f, 0.f, 0.f, 0.f};
#pragma unroll
            for (int ks = 0; ks < 8; ++ks) {
                const int ei = n * 256 + ((ks * 32 + kgrp) ^ nswz);
                const short8 bs = *reinterpret_cast<const short8*>(&scol[ei]);
                acc = __builtin_amdgcn_mfma_f32_16x16x32_bf16(aq[ks], bs, acc, 0, 0, 0);
            }
            float a0 = 0.f, a1 = 0.f, a2 = 0.f, a3 = 0.f;
#pragma unroll
            for (int j = 0; j < O_; ++j) {
                const float uj = (j < 4) ? s01[j & 3] : s23[j & 3];
                const int ix = (int)((ip >> (8 * j)) & 0x7Fu);
                const float4 qv = *reinterpret_cast<const float4*>(qtb + ix * M_ + m0);
                a0 = fmaf(uj, qv.x, a0);
                a1 = fmaf(uj, qv.y, a1);
                a2 = fmaf(uj, qv.z, a2);
                a3 = fmaf(uj, qv.w, a3);
            }
            acc[0] += a0; acc[1] += a1; acc[2] += a2; acc[3] += a3;
            float* ob = out + ((size_t)(b * HQ_ + hq) * N_ + (n0 + n)) * M_ + m0;
            *reinterpret_cast<f32x4*>(ob) = acc;
        }
    }
}

extern "C" void kernel_launch(void* const* d_in, const int* in_sizes, int n_in,
                              void* d_out, int out_size, void* d_ws, size_t ws_size,
                              hipStream_t stream) {
    const float* query = (const float*)d_in[0];  // [B][HQ][M][D]
    const float* data  = (const float*)d_in[1];  // [B][HK][N][D]
    const float* proj  = (const float*)d_in[2];  // [D][S]
    const int*   oidx  = (const int*)d_in[3];    // [B][HK][N][O]

    float* out = (float*)d_out;                  // [B][HQ][N][M]

    char* ws = (char*)d_ws;
    unsigned short* sqHi  = (unsigned short*)(ws);                     // 1 MB
    float*          qT    = (float*)(ws + (1 << 20));                  // 1 MB
    unsigned short* PtHi  = (unsigned short*)(ws + (2 << 20));         // 64 KB
    unsigned short* PtLo  = (unsigned short*)(ws + (2 << 20) + (64 << 10));   // 64 KB
    float*          Pt32  = (float*)(ws + (2 << 20) + (128 << 10));    // 128 KB
    unsigned long long* wordsg = (unsigned long long*)(ws + (3 << 20)); // 8 MB
    float*          sning = (float*)(ws + (11 << 20));                 // 1 MB
    float*          su2g  = (float*)(ws + (12 << 20));                 // 8 MB
    unsigned long long* sidxpg = (unsigned long long*)(ws + (20 << 20)); // 2 MB

    qjl_prept<<<dim3(D_), dim3(S_), 0, stream>>>(proj, PtHi, PtLo, Pt32);
    qjl_sketch_q<<<dim3(B_ * HQ_), dim3(256), 0, stream>>>(query, proj, sqHi, qT);
    qjl_signs<<<dim3(N_ / TN, HK_, B_), dim3(256), 0, stream>>>(
        data, proj, oidx, PtHi, PtLo, Pt32, wordsg, sning, su2g, sidxpg);
    qjl_out<<<dim3(N_ / TN, HK_, B_), dim3(256), 0, stream>>>(
        sqHi, qT, wordsg, sning, su2g, sidxpg, out);
}